// Round 2
// baseline (613.723 us; speedup 1.0000x reference)
//
#include <hip/hip_runtime.h>
#include <math.h>

#define B    16
#define N    20000
#define E    640000
#define NREG 2000
#define DIN  128
#define F    32
#define NEG  0.2f
#define BF   (B * F)          // 512 floats per node row; 256 uints in bf16
#define NCHUNK 8
#define CS   2500             // nodes per chunk (2500*1KB = 2.44 MB repu slice)
#define HIST_BLOCKS 1024
#define SCAT_BLOCKS 1024

typedef unsigned int uint;

__device__ inline uint bf16pair(float a, float b) {
    uint ua = __float_as_uint(a); ua = (ua + 0x7fffu + ((ua >> 16) & 1u)) >> 16;
    uint ub = __float_as_uint(b); ub = (ub + 0x7fffu + ((ub >> 16) & 1u)) >> 16;
    return ua | (ub << 16);
}
__device__ inline float bf16lo(uint v) { return __uint_as_float(v << 16); }
__device__ inline float bf16hi(uint v) { return __uint_as_float(v & 0xffff0000u); }

// ---------------- prep1: fused  hist | roff | cedge ----------------
// blocks [0, HIST_BLOCKS): dst histogram (random atomics)
// blocks [HIST_BLOCKS, HIST_BLOCKS+8): regulon offsets via binary search
// block  HIST_BLOCKS+8: scalar c_edge = dot(lin_edge, att_edge)
__global__ __launch_bounds__(256) void k_prep1(const int* __restrict__ esrc,
                                               const int* __restrict__ edst,
                                               const float* __restrict__ lin_edge,
                                               const float* __restrict__ att_edge,
                                               int* __restrict__ counts,
                                               int* __restrict__ roff,
                                               float* __restrict__ cedge) {
    int blk = blockIdx.x;
    int t = threadIdx.x;
    if (blk < HIST_BLOCKS) {
        int e = blk * 256 + t;
        for (; e < E; e += HIST_BLOCKS * 256)
            atomicAdd(&counts[edst[e]], 1);
    } else if (blk < HIST_BLOCKS + 8) {
        int r = (blk - HIST_BLOCKS) * 256 + t;
        if (r > NREG) return;
        int lo = 0, hi = E;
        while (lo < hi) {
            int mid = (lo + hi) >> 1;
            if (esrc[mid] < r) lo = mid + 1; else hi = mid;
        }
        roff[r] = lo;
    } else {
        if (t == 0) {
            float s = 0.f;
            for (int f = 0; f < F; ++f) s += lin_edge[f] * att_edge[f];
            *cedge = s;
        }
    }
}

// ---------------- single-block exclusive scan ----------------
__global__ __launch_bounds__(1024) void k_scan(const int* __restrict__ in,
                                               int* __restrict__ out, int n) {
    __shared__ int sh[1024];
    int t = threadIdx.x;
    int chunk = (n + 1023) / 1024;
    int lo = t * chunk;
    int hi = lo + chunk; if (hi > n) hi = n;
    int local = 0;
    for (int i = lo; i < hi; ++i) local += in[i];
    sh[t] = local;
    __syncthreads();
    for (int d = 1; d < 1024; d <<= 1) {
        int v = (t >= d) ? sh[t - d] : 0;
        __syncthreads();
        sh[t] += v;
        __syncthreads();
    }
    int run = (t == 0) ? 0 : sh[t - 1];
    for (int i = lo; i < hi; ++i) { out[i] = run; run += in[i]; }
    if (t == 1023) out[n] = sh[1023];
}

// ---------------- prep2: fused  scatter | bucket ----------------
// blocks [0, SCAT_BLOCKS): scatter edges into CSR-by-dst
// blocks [SCAT_BLOCKS, SCAT_BLOCKS+NREG): per-regulon chunk bucketing
__global__ __launch_bounds__(256) void k_prep2(const int* __restrict__ esrc,
                                               const int* __restrict__ edst,
                                               const int* __restrict__ off,
                                               int* __restrict__ cursor,
                                               int* __restrict__ csr_src,
                                               int* __restrict__ pos_of_e,
                                               const int* __restrict__ roff,
                                               int* __restrict__ boff,
                                               int* __restrict__ pe_dst) {
    __shared__ int cnt[NCHUNK], pref[NCHUNK], cur[NCHUNK];
    int blk = blockIdx.x;
    int t = threadIdx.x;
    if (blk < SCAT_BLOCKS) {
        int e = blk * 256 + t;
        for (; e < E; e += SCAT_BLOCKS * 256) {
            int d = edst[e];
            int pos = off[d] + atomicAdd(&cursor[d], 1);
            csr_src[pos] = esrc[e];
            pos_of_e[e] = pos;
        }
    } else {
        int r = blk - SCAT_BLOCKS;
        int lo = roff[r], hi = roff[r + 1];
        if (t < NCHUNK) { cnt[t] = 0; cur[t] = 0; }
        __syncthreads();
        for (int e = lo + t; e < hi; e += 256)
            atomicAdd(&cnt[edst[e] / CS], 1);
        __syncthreads();
        if (t == 0) {
            int run = 0;
            #pragma unroll
            for (int c = 0; c < NCHUNK; ++c) { pref[c] = run; run += cnt[c]; }
        }
        __syncthreads();
        if (t < NCHUNK) boff[r * NCHUNK + t] = lo + pref[t];
        if (r == 0 && t == 0) boff[NREG * NCHUNK] = E;
        for (int e = lo + t; e < hi; e += 256) {
            int d = edst[e];
            int c = d / CS;
            int pos = lo + pref[c] + atomicAdd(&cur[c], 1);
            pe_dst[pos] = d;
        }
    }
}

// ---------------- fused: eattr tile -> alpha -> exp -> wbuf[csr_pos][B]
//                  + per-batch eattr mean (folded, saves a full 41MB pass) ----
__global__ __launch_bounds__(256) void k_edgew(const float* __restrict__ eattr,
                                               const int* __restrict__ esrc,
                                               const int* __restrict__ edst,
                                               const int* __restrict__ pos_of_e,
                                               const float* __restrict__ a_src,
                                               const float* __restrict__ a_dst,
                                               const float* __restrict__ cedge,
                                               float* __restrict__ wbuf,
                                               float* __restrict__ meanb) {
    __shared__ float tile[B][257];
    __shared__ int ssrc[256], sdst[256], spos[256];
    int e0 = blockIdx.x * 256;
    int t = threadIdx.x;
    #pragma unroll
    for (int b = 0; b < B; ++b)
        tile[b][t] = eattr[(size_t)b * E + e0 + t];
    ssrc[t] = esrc[e0 + t];
    sdst[t] = edst[e0 + t];
    spos[t] = pos_of_e[e0 + t];
    __syncthreads();
    // folded mean: 16 lanes per batch reduce the staged tile
    {
        int bb = t >> 4, fp = t & 15;
        float ms = 0.f;
        #pragma unroll
        for (int q = 0; q < 16; ++q) ms += tile[bb][fp + 16 * q];
        #pragma unroll
        for (int d = 8; d > 0; d >>= 1) ms += __shfl_down(ms, d, 16);
        if (fp == 0) atomicAdd(&meanb[bb], ms);
    }
    float c = *cedge;
    #pragma unroll
    for (int p = 0; p < 16; ++p) {
        int idx = p * 256 + t;
        int el = idx >> 4;
        int bb = idx & 15;
        float a = a_src[(size_t)ssrc[el] * B + bb]
                + a_dst[(size_t)sdst[el] * B + bb]
                + tile[bb][el] * c;
        a = a > 0.f ? a : NEG * a;
        wbuf[(size_t)spos[el] * B + bb] = __expf(a);
    }
}

// ---------------- h = x @ W -> bf16 [n][B][F]; fused a_src/a_dst ----------------
#define XS_LD 260
__global__ __launch_bounds__(256) void k_gemm(const float* __restrict__ x,
                                              const float* __restrict__ W,
                                              const float* __restrict__ att_src,
                                              const float* __restrict__ att_dst,
                                              uint* __restrict__ hu,
                                              float* __restrict__ a_src,
                                              float* __restrict__ a_dst) {
    __shared__ float Ws[DIN * F];
    __shared__ float xs[32 * XS_LD];
    int t = threadIdx.x;
    int row0 = blockIdx.x * 256;      // flattened b*N + n
    #pragma unroll
    for (int j = 0; j < 4; ++j) {
        int idx = (t + 256 * j) * 4;
        *(float4*)&Ws[idx] = *(const float4*)&W[idx];
    }
    const int lr = t & 63;
    const int fg = t >> 6;            // wave-uniform
    float acc[4][8];
    #pragma unroll
    for (int i = 0; i < 4; ++i)
        #pragma unroll
        for (int j = 0; j < 8; ++j) acc[i][j] = 0.f;

    for (int kc = 0; kc < 4; ++kc) {
        __syncthreads();
        #pragma unroll
        for (int j = 0; j < 8; ++j) {
            int p = t + 256 * j;
            int row = p >> 3;
            int kk  = (p & 7) * 4;
            float4 g = *(const float4*)&x[(size_t)(row0 + row) * DIN + kc * 32 + kk];
            xs[(kk + 0) * XS_LD + row] = g.x;
            xs[(kk + 1) * XS_LD + row] = g.y;
            xs[(kk + 2) * XS_LD + row] = g.z;
            xs[(kk + 3) * XS_LD + row] = g.w;
        }
        __syncthreads();
        #pragma unroll
        for (int k = 0; k < 32; ++k) {
            float4 xv = *(float4*)&xs[k * XS_LD + 4 * lr];
            float4 w0 = *(float4*)&Ws[(kc * 32 + k) * F + fg * 8];
            float4 w1 = *(float4*)&Ws[(kc * 32 + k) * F + fg * 8 + 4];
            float xr[4] = {xv.x, xv.y, xv.z, xv.w};
            float wr[8] = {w0.x, w0.y, w0.z, w0.w, w1.x, w1.y, w1.z, w1.w};
            #pragma unroll
            for (int i = 0; i < 4; ++i)
                #pragma unroll
                for (int j = 0; j < 8; ++j)
                    acc[i][j] = fmaf(xr[i], wr[j], acc[i][j]);
        }
    }
    #pragma unroll
    for (int i = 0; i < 4; ++i) {
        int row = row0 + lr * 4 + i;
        int b = row / N;
        int n = row - b * N;
        uint4 o;
        o.x = bf16pair(acc[i][0], acc[i][1]);
        o.y = bf16pair(acc[i][2], acc[i][3]);
        o.z = bf16pair(acc[i][4], acc[i][5]);
        o.w = bf16pair(acc[i][6], acc[i][7]);
        *(uint4*)&hu[(size_t)n * 256 + b * 16 + fg * 4] = o;
    }
    float* red = xs;
    __syncthreads();
    #pragma unroll
    for (int i = 0; i < 4; ++i) {
        float s1 = 0.f, s2 = 0.f;
        #pragma unroll
        for (int j = 0; j < 8; ++j) {
            float as = att_src[fg * 8 + j];
            float ad = att_dst[fg * 8 + j];
            s1 = fmaf(acc[i][j], as, s1);
            s2 = fmaf(acc[i][j], ad, s2);
        }
        red[fg * 256 + lr * 4 + i]        = s1;
        red[1024 + fg * 256 + lr * 4 + i] = s2;
    }
    __syncthreads();
    {
        float s1 = red[t] + red[256 + t] + red[512 + t] + red[768 + t];
        float s2 = red[1024 + t] + red[1280 + t] + red[1536 + t] + red[1792 + t];
        int row = row0 + t;
        int b = row / N;
        int n = row - b * N;
        a_src[(size_t)n * B + b] = s1;
        a_dst[(size_t)n * B + b] = s2;
    }
}

// ---------------- rep: weighted aggregate, 8-deep pipelined gather ----------------
__global__ __launch_bounds__(256) void k_rep(
    const uint* __restrict__ hu, const float* __restrict__ a_src,
    const float* __restrict__ a_dst, const float* __restrict__ wbuf,
    const float* __restrict__ bias, const float* __restrict__ meanb,
    const float* __restrict__ cedge, const int* __restrict__ dst_off,
    const int* __restrict__ csr_src, uint* __restrict__ repu) {
    int i = blockIdx.x;
    int t = threadIdx.x;
    int b  = t >> 4;
    int fp = t & 15;
    float c = *cedge;
    float meanv = meanb[b] * (1.f / (float)E);
    float al = a_src[(size_t)i * B + b] + a_dst[(size_t)i * B + b] + meanv * c;
    al = al > 0.f ? al : NEG * al;
    float s = __expf(al);
    uint hv = hu[(size_t)i * 256 + t];
    float acc0 = s * bf16lo(hv);
    float acc1 = s * bf16hi(hv);
    int lo = dst_off[i], hi = dst_off[i + 1];
    int j = lo;
    for (; j + 8 <= hi; j += 8) {
        int   sv[8];
        float wv[8];
        uint  vv[8];
        #pragma unroll
        for (int q = 0; q < 8; ++q) sv[q] = csr_src[j + q];
        #pragma unroll
        for (int q = 0; q < 8; ++q) wv[q] = wbuf[(size_t)(j + q) * B + b];
        #pragma unroll
        for (int q = 0; q < 8; ++q) vv[q] = hu[(size_t)sv[q] * 256 + t];
        #pragma unroll
        for (int q = 0; q < 8; ++q) {
            s += wv[q];
            acc0 = fmaf(wv[q], bf16lo(vv[q]), acc0);
            acc1 = fmaf(wv[q], bf16hi(vv[q]), acc1);
        }
    }
    for (; j + 4 <= hi; j += 4) {
        int s0 = csr_src[j], s1 = csr_src[j+1], s2 = csr_src[j+2], s3 = csr_src[j+3];
        float w0 = wbuf[(size_t)(j+0) * B + b];
        float w1 = wbuf[(size_t)(j+1) * B + b];
        float w2 = wbuf[(size_t)(j+2) * B + b];
        float w3 = wbuf[(size_t)(j+3) * B + b];
        uint v0 = hu[(size_t)s0 * 256 + t];
        uint v1 = hu[(size_t)s1 * 256 + t];
        uint v2 = hu[(size_t)s2 * 256 + t];
        uint v3 = hu[(size_t)s3 * 256 + t];
        s += w0 + w1 + w2 + w3;
        acc0 = fmaf(w0, bf16lo(v0), acc0);
        acc1 = fmaf(w0, bf16hi(v0), acc1);
        acc0 = fmaf(w1, bf16lo(v1), acc0);
        acc1 = fmaf(w1, bf16hi(v1), acc1);
        acc0 = fmaf(w2, bf16lo(v2), acc0);
        acc1 = fmaf(w2, bf16hi(v2), acc1);
        acc0 = fmaf(w3, bf16lo(v3), acc0);
        acc1 = fmaf(w3, bf16hi(v3), acc1);
    }
    for (; j < hi; ++j) {
        int sj = csr_src[j];
        float wv = wbuf[(size_t)j * B + b];
        uint v = hu[(size_t)sj * 256 + t];
        s += wv;
        acc0 = fmaf(wv, bf16lo(v), acc0);
        acc1 = fmaf(wv, bf16hi(v), acc1);
    }
    float inv = 1.f / s;
    repu[(size_t)i * 256 + t] = bf16pair(acc0 * inv + bias[2 * fp],
                                         acc1 * inv + bias[2 * fp + 1]);
}

// ---------------- chunked pooling: block = (chunk, regulon), 8-deep pipeline ----------------
__global__ __launch_bounds__(256) void k_pool(const uint* __restrict__ repu,
                                              const int* __restrict__ boff,
                                              const int* __restrict__ pe_dst,
                                              float* __restrict__ partial) {
    int key = blockIdx.x;            // c * NREG + r (chunk-major dispatch)
    int c = key / NREG;
    int r = key - c * NREG;
    int idx = r * NCHUNK + c;        // boff is regulon-major
    int t = threadIdx.x;
    int lo = boff[idx], hi = boff[idx + 1];
    float acc0 = 0.f, acc1 = 0.f;
    int e = lo;
    for (; e + 8 <= hi; e += 8) {
        int d0 = pe_dst[e+0], d1 = pe_dst[e+1], d2 = pe_dst[e+2], d3 = pe_dst[e+3];
        int d4 = pe_dst[e+4], d5 = pe_dst[e+5], d6 = pe_dst[e+6], d7 = pe_dst[e+7];
        uint v0 = repu[(size_t)d0 * 256 + t];
        uint v1 = repu[(size_t)d1 * 256 + t];
        uint v2 = repu[(size_t)d2 * 256 + t];
        uint v3 = repu[(size_t)d3 * 256 + t];
        uint v4 = repu[(size_t)d4 * 256 + t];
        uint v5 = repu[(size_t)d5 * 256 + t];
        uint v6 = repu[(size_t)d6 * 256 + t];
        uint v7 = repu[(size_t)d7 * 256 + t];
        acc0 += (bf16lo(v0) + bf16lo(v1)) + (bf16lo(v2) + bf16lo(v3))
              + (bf16lo(v4) + bf16lo(v5)) + (bf16lo(v6) + bf16lo(v7));
        acc1 += (bf16hi(v0) + bf16hi(v1)) + (bf16hi(v2) + bf16hi(v3))
              + (bf16hi(v4) + bf16hi(v5)) + (bf16hi(v6) + bf16hi(v7));
    }
    for (; e < hi; ++e) {
        int d = pe_dst[e];
        uint v = repu[(size_t)d * 256 + t];
        acc0 += bf16lo(v);
        acc1 += bf16hi(v);
    }
    float2 o = {acc0, acc1};
    *(float2*)&partial[((size_t)r * NCHUNK + c) * BF + 2 * t] = o;
}

__global__ __launch_bounds__(256) void k_combine(const uint* __restrict__ repu,
                                                 const float* __restrict__ partial,
                                                 float* __restrict__ out) {
    int r = blockIdx.x;
    int t = threadIdx.x;
    int b  = t >> 4;
    int fp = t & 15;
    uint v = repu[(size_t)r * 256 + t];      // self term
    float s0 = bf16lo(v), s1 = bf16hi(v);
    #pragma unroll
    for (int c = 0; c < NCHUNK; ++c) {
        float2 p = *(const float2*)&partial[((size_t)r * NCHUNK + c) * BF + 2 * t];
        s0 += p.x; s1 += p.y;
    }
    float2 o = {s0, s1};
    *(float2*)&out[(size_t)b * NREG * F + r * F + 2 * fp] = o;
}

extern "C" void kernel_launch(void* const* d_in, const int* in_sizes, int n_in,
                              void* d_out, int out_size, void* d_ws, size_t ws_size,
                              hipStream_t stream) {
    const float* x        = (const float*)d_in[0];
    const float* eattr    = (const float*)d_in[1];
    const float* W        = (const float*)d_in[2];
    const float* att_src  = (const float*)d_in[3];
    const float* att_dst  = (const float*)d_in[4];
    const float* lin_edge = (const float*)d_in[5];
    const float* att_edge = (const float*)d_in[6];
    const float* bias     = (const float*)d_in[7];
    const int*   esrc     = (const int*)d_in[8];
    const int*   edst     = (const int*)d_in[9];
    float* out = (float*)d_out;

    char* ws = (char*)d_ws;
    size_t off = 0;
    auto alloc = [&](size_t bytes) -> void* {
        void* p = ws + off;
        off = (off + bytes + 255) & ~(size_t)255;
        return p;
    };
    uint*  hu    = (uint*)alloc((size_t)N * 256 * 4);          // 20.5 MB bf16 h
    uint*  repu  = (uint*)alloc((size_t)N * 256 * 4);          // 20.5 MB bf16 rep
    float* wbuf  = (float*)alloc((size_t)E * B * 4);           // 41 MB [csr_pos][B]
    float* a_src = (float*)alloc((size_t)N * B * 4);
    float* a_dst = (float*)alloc((size_t)N * B * 4);
    int* dst_off = (int*)alloc((size_t)(N + 1) * 4);
    int* roff    = (int*)alloc((size_t)(NREG + 1) * 4);
    int* csr_src = (int*)alloc((size_t)E * 4);
    int* pos_of_e= (int*)alloc((size_t)E * 4);
    int* pe_dst  = (int*)alloc((size_t)E * 4);
    int* boff    = (int*)alloc((size_t)(NREG * NCHUNK + 1) * 4);
    char* zbase   = ws + off;
    int* counts   = (int*)alloc((size_t)N * 4);
    int* cursor   = (int*)alloc((size_t)N * 4);
    float* meanb  = (float*)alloc((size_t)B * 4);
    float* cedge  = (float*)alloc(4);
    size_t zbytes = (size_t)((ws + off) - zbase);
    float* partial = wbuf;   // alias: wbuf dead after k_rep; 32.8 MB <= 41 MB

    hipMemsetAsync(zbase, 0, zbytes, stream);

    k_prep1<<<HIST_BLOCKS + 8 + 1, 256, 0, stream>>>(esrc, edst, lin_edge,
                                                     att_edge, counts, roff, cedge);
    k_scan<<<1, 1024, 0, stream>>>(counts, dst_off, N);
    k_prep2<<<SCAT_BLOCKS + NREG, 256, 0, stream>>>(esrc, edst, dst_off, cursor,
                                                    csr_src, pos_of_e,
                                                    roff, boff, pe_dst);
    k_gemm<<<(B * N) / 256, 256, 0, stream>>>(x, W, att_src, att_dst,
                                              hu, a_src, a_dst);
    k_edgew<<<E / 256, 256, 0, stream>>>(eattr, esrc, edst, pos_of_e,
                                         a_src, a_dst, cedge, wbuf, meanb);
    k_rep<<<N, 256, 0, stream>>>(hu, a_src, a_dst, wbuf, bias, meanb, cedge,
                                 dst_off, csr_src, repu);
    k_pool<<<NREG * NCHUNK, 256, 0, stream>>>(repu, boff, pe_dst, partial);
    k_combine<<<NREG, 256, 0, stream>>>(repu, partial, out);
}

// Round 3
// 551.899 us; speedup vs baseline: 1.1120x; 1.1120x over previous
//
#include <hip/hip_runtime.h>
#include <math.h>

#define B    16
#define N    20000
#define E    640000
#define NREG 2000
#define DIN  128
#define F    32
#define NEG  0.2f
#define BF   (B * F)          // 512 floats per node row; 256 uints in bf16
#define NCHUNK 8
#define CS   2500             // nodes per chunk (2500*1KB = 2.44 MB repu slice)
#define HIST_BLOCKS 1024
#define SCAT_BLOCKS 1024

typedef unsigned int uint;

__device__ inline uint bf16pair(float a, float b) {
    uint ua = __float_as_uint(a); ua = (ua + 0x7fffu + ((ua >> 16) & 1u)) >> 16;
    uint ub = __float_as_uint(b); ub = (ub + 0x7fffu + ((ub >> 16) & 1u)) >> 16;
    return ua | (ub << 16);
}
__device__ inline float bf16lo(uint v) { return __uint_as_float(v << 16); }
__device__ inline float bf16hi(uint v) { return __uint_as_float(v & 0xffff0000u); }

// ---------------- prep1: fused  hist+mean | roff | cedge ----------------
// blocks [0, HIST_BLOCKS): dst histogram (random atomics) + per-batch eattr mean
//   (64 blocks per batch, contiguous slice, ONE atomic per block)
// blocks [HIST_BLOCKS, HIST_BLOCKS+8): regulon offsets via binary search
// block  HIST_BLOCKS+8: scalar c_edge = dot(lin_edge, att_edge)
__global__ __launch_bounds__(256) void k_prep1(const int* __restrict__ esrc,
                                               const int* __restrict__ edst,
                                               const float* __restrict__ eattr,
                                               const float* __restrict__ lin_edge,
                                               const float* __restrict__ att_edge,
                                               int* __restrict__ counts,
                                               int* __restrict__ roff,
                                               float* __restrict__ meanb,
                                               float* __restrict__ cedge) {
    int blk = blockIdx.x;
    int t = threadIdx.x;
    if (blk < HIST_BLOCKS) {
        // ---- mean partial: batch blk>>6, slice blk&63 (10000 floats contiguous)
        {
            int b = blk >> 6, sl = blk & 63;
            const float4* base = (const float4*)(eattr + (size_t)b * E + sl * 10000);
            float s = 0.f;
            for (int i = t; i < 2500; i += 256) {
                float4 v = base[i];
                s += (v.x + v.y) + (v.z + v.w);
            }
            __shared__ float sh[256];
            sh[t] = s;
            __syncthreads();
            for (int d = 128; d > 0; d >>= 1) {
                if (t < d) sh[t] += sh[t + d];
                __syncthreads();
            }
            if (t == 0) atomicAdd(&meanb[b], sh[0]);
        }
        // ---- histogram
        for (int e = blk * 256 + t; e < E; e += HIST_BLOCKS * 256)
            atomicAdd(&counts[edst[e]], 1);
    } else if (blk < HIST_BLOCKS + 8) {
        int r = (blk - HIST_BLOCKS) * 256 + t;
        if (r > NREG) return;
        int lo = 0, hi = E;
        while (lo < hi) {
            int mid = (lo + hi) >> 1;
            if (esrc[mid] < r) lo = mid + 1; else hi = mid;
        }
        roff[r] = lo;
    } else {
        if (t == 0) {
            float s = 0.f;
            for (int f = 0; f < F; ++f) s += lin_edge[f] * att_edge[f];
            *cedge = s;
        }
    }
}

// ---------------- single-block exclusive scan ----------------
__global__ __launch_bounds__(1024) void k_scan(const int* __restrict__ in,
                                               int* __restrict__ out, int n) {
    __shared__ int sh[1024];
    int t = threadIdx.x;
    int chunk = (n + 1023) / 1024;
    int lo = t * chunk;
    int hi = lo + chunk; if (hi > n) hi = n;
    int local = 0;
    for (int i = lo; i < hi; ++i) local += in[i];
    sh[t] = local;
    __syncthreads();
    for (int d = 1; d < 1024; d <<= 1) {
        int v = (t >= d) ? sh[t - d] : 0;
        __syncthreads();
        sh[t] += v;
        __syncthreads();
    }
    int run = (t == 0) ? 0 : sh[t - 1];
    for (int i = lo; i < hi; ++i) { out[i] = run; run += in[i]; }
    if (t == 1023) out[n] = sh[1023];
}

// ---------------- prep2: fused  scatter | bucket ----------------
// blocks [0, SCAT_BLOCKS): scatter edges into CSR-by-dst (src node + edge id)
// blocks [SCAT_BLOCKS, SCAT_BLOCKS+NREG): per-regulon chunk bucketing
__global__ __launch_bounds__(256) void k_prep2(const int* __restrict__ esrc,
                                               const int* __restrict__ edst,
                                               const int* __restrict__ off,
                                               int* __restrict__ cursor,
                                               int* __restrict__ csr_src,
                                               int* __restrict__ csr_eid,
                                               const int* __restrict__ roff,
                                               int* __restrict__ boff,
                                               int* __restrict__ pe_dst) {
    __shared__ int cnt[NCHUNK], pref[NCHUNK], cur[NCHUNK];
    int blk = blockIdx.x;
    int t = threadIdx.x;
    if (blk < SCAT_BLOCKS) {
        int e = blk * 256 + t;
        for (; e < E; e += SCAT_BLOCKS * 256) {
            int d = edst[e];
            int pos = off[d] + atomicAdd(&cursor[d], 1);
            csr_src[pos] = esrc[e];
            csr_eid[pos] = e;
        }
    } else {
        int r = blk - SCAT_BLOCKS;
        int lo = roff[r], hi = roff[r + 1];
        if (t < NCHUNK) { cnt[t] = 0; cur[t] = 0; }
        __syncthreads();
        for (int e = lo + t; e < hi; e += 256)
            atomicAdd(&cnt[edst[e] / CS], 1);
        __syncthreads();
        if (t == 0) {
            int run = 0;
            #pragma unroll
            for (int c = 0; c < NCHUNK; ++c) { pref[c] = run; run += cnt[c]; }
        }
        __syncthreads();
        if (t < NCHUNK) boff[r * NCHUNK + t] = lo + pref[t];
        if (r == 0 && t == 0) boff[NREG * NCHUNK] = E;
        for (int e = lo + t; e < hi; e += 256) {
            int d = edst[e];
            int c = d / CS;
            int pos = lo + pref[c] + atomicAdd(&cur[c], 1);
            pe_dst[pos] = d;
        }
    }
}

// ---------------- coalesced transpose: ew[e][b] = c * eattr[b][e] ----------------
__global__ __launch_bounds__(256) void k_trans(const float* __restrict__ eattr,
                                               const float* __restrict__ cedge,
                                               float* __restrict__ ew) {
    __shared__ float tile[256][17];
    int e0 = blockIdx.x * 256;
    int t = threadIdx.x;
    #pragma unroll
    for (int b = 0; b < B; ++b)
        tile[t][b] = eattr[(size_t)b * E + e0 + t];
    __syncthreads();
    float c = *cedge;
    #pragma unroll
    for (int p = 0; p < 4; ++p) {
        int i4 = (p * 256 + t) * 4;
        int el = i4 >> 4, b0 = i4 & 15;
        float4 o;
        o.x = c * tile[el][b0 + 0];
        o.y = c * tile[el][b0 + 1];
        o.z = c * tile[el][b0 + 2];
        o.w = c * tile[el][b0 + 3];
        *(float4*)&ew[(size_t)e0 * 16 + i4] = o;
    }
}

// ---------------- h = x @ W -> bf16 [n][B][F]; fused a_src/a_dst ----------------
#define XS_LD 260
__global__ __launch_bounds__(256) void k_gemm(const float* __restrict__ x,
                                              const float* __restrict__ W,
                                              const float* __restrict__ att_src,
                                              const float* __restrict__ att_dst,
                                              uint* __restrict__ hu,
                                              float* __restrict__ a_src,
                                              float* __restrict__ a_dst) {
    __shared__ float Ws[DIN * F];
    __shared__ float xs[32 * XS_LD];
    int t = threadIdx.x;
    int row0 = blockIdx.x * 256;      // flattened b*N + n
    #pragma unroll
    for (int j = 0; j < 4; ++j) {
        int idx = (t + 256 * j) * 4;
        *(float4*)&Ws[idx] = *(const float4*)&W[idx];
    }
    const int lr = t & 63;
    const int fg = t >> 6;            // wave-uniform
    float acc[4][8];
    #pragma unroll
    for (int i = 0; i < 4; ++i)
        #pragma unroll
        for (int j = 0; j < 8; ++j) acc[i][j] = 0.f;

    for (int kc = 0; kc < 4; ++kc) {
        __syncthreads();
        #pragma unroll
        for (int j = 0; j < 8; ++j) {
            int p = t + 256 * j;
            int row = p >> 3;
            int kk  = (p & 7) * 4;
            float4 g = *(const float4*)&x[(size_t)(row0 + row) * DIN + kc * 32 + kk];
            xs[(kk + 0) * XS_LD + row] = g.x;
            xs[(kk + 1) * XS_LD + row] = g.y;
            xs[(kk + 2) * XS_LD + row] = g.z;
            xs[(kk + 3) * XS_LD + row] = g.w;
        }
        __syncthreads();
        #pragma unroll
        for (int k = 0; k < 32; ++k) {
            float4 xv = *(float4*)&xs[k * XS_LD + 4 * lr];
            float4 w0 = *(float4*)&Ws[(kc * 32 + k) * F + fg * 8];
            float4 w1 = *(float4*)&Ws[(kc * 32 + k) * F + fg * 8 + 4];
            float xr[4] = {xv.x, xv.y, xv.z, xv.w};
            float wr[8] = {w0.x, w0.y, w0.z, w0.w, w1.x, w1.y, w1.z, w1.w};
            #pragma unroll
            for (int i = 0; i < 4; ++i)
                #pragma unroll
                for (int j = 0; j < 8; ++j)
                    acc[i][j] = fmaf(xr[i], wr[j], acc[i][j]);
        }
    }
    #pragma unroll
    for (int i = 0; i < 4; ++i) {
        int row = row0 + lr * 4 + i;
        int b = row / N;
        int n = row - b * N;
        uint4 o;
        o.x = bf16pair(acc[i][0], acc[i][1]);
        o.y = bf16pair(acc[i][2], acc[i][3]);
        o.z = bf16pair(acc[i][4], acc[i][5]);
        o.w = bf16pair(acc[i][6], acc[i][7]);
        *(uint4*)&hu[(size_t)n * 256 + b * 16 + fg * 4] = o;
    }
    float* red = xs;
    __syncthreads();
    #pragma unroll
    for (int i = 0; i < 4; ++i) {
        float s1 = 0.f, s2 = 0.f;
        #pragma unroll
        for (int j = 0; j < 8; ++j) {
            float as = att_src[fg * 8 + j];
            float ad = att_dst[fg * 8 + j];
            s1 = fmaf(acc[i][j], as, s1);
            s2 = fmaf(acc[i][j], ad, s2);
        }
        red[fg * 256 + lr * 4 + i]        = s1;
        red[1024 + fg * 256 + lr * 4 + i] = s2;
    }
    __syncthreads();
    {
        float s1 = red[t] + red[256 + t] + red[512 + t] + red[768 + t];
        float s2 = red[1024 + t] + red[1280 + t] + red[1536 + t] + red[1792 + t];
        int row = row0 + t;
        int b = row / N;
        int n = row - b * N;
        a_src[(size_t)n * B + b] = s1;
        a_dst[(size_t)n * B + b] = s2;
    }
}

// ---------------- rep: inline alpha+exp, 8-deep pipelined gather ----------------
__global__ __launch_bounds__(256) void k_rep(
    const uint* __restrict__ hu, const float* __restrict__ a_src,
    const float* __restrict__ a_dst, const float* __restrict__ ew,
    const int* __restrict__ csr_eid,
    const float* __restrict__ bias, const float* __restrict__ meanb,
    const float* __restrict__ cedge, const int* __restrict__ dst_off,
    const int* __restrict__ csr_src, uint* __restrict__ repu) {
    int i = blockIdx.x;
    int t = threadIdx.x;
    int b  = t >> 4;
    int fp = t & 15;
    float c = *cedge;
    float adst = a_dst[(size_t)i * B + b];
    float meanv = meanb[b] * (1.f / (float)E);
    // self-loop term
    float al = a_src[(size_t)i * B + b] + adst + meanv * c;
    al = al > 0.f ? al : NEG * al;
    float s = __expf(al);
    uint hv = hu[(size_t)i * 256 + t];
    float acc0 = s * bf16lo(hv);
    float acc1 = s * bf16hi(hv);
    int lo = dst_off[i], hi = dst_off[i + 1];
    int j = lo;
    for (; j + 8 <= hi; j += 8) {
        int   sv[8];
        int   ev[8];
        float av[8];
        float wv[8];
        uint  vv[8];
        #pragma unroll
        for (int q = 0; q < 8; ++q) sv[q] = csr_src[j + q];
        #pragma unroll
        for (int q = 0; q < 8; ++q) ev[q] = csr_eid[j + q];
        #pragma unroll
        for (int q = 0; q < 8; ++q) av[q] = a_src[(size_t)sv[q] * B + b];
        #pragma unroll
        for (int q = 0; q < 8; ++q) wv[q] = ew[(size_t)ev[q] * B + b];
        #pragma unroll
        for (int q = 0; q < 8; ++q) vv[q] = hu[(size_t)sv[q] * 256 + t];
        #pragma unroll
        for (int q = 0; q < 8; ++q) {
            float a2 = av[q] + adst + wv[q];
            a2 = a2 > 0.f ? a2 : NEG * a2;
            float w = __expf(a2);
            s += w;
            acc0 = fmaf(w, bf16lo(vv[q]), acc0);
            acc1 = fmaf(w, bf16hi(vv[q]), acc1);
        }
    }
    for (; j < hi; ++j) {
        int sj = csr_src[j];
        int ej = csr_eid[j];
        float a2 = a_src[(size_t)sj * B + b] + adst + ew[(size_t)ej * B + b];
        a2 = a2 > 0.f ? a2 : NEG * a2;
        float w = __expf(a2);
        uint v = hu[(size_t)sj * 256 + t];
        s += w;
        acc0 = fmaf(w, bf16lo(v), acc0);
        acc1 = fmaf(w, bf16hi(v), acc1);
    }
    float inv = 1.f / s;
    repu[(size_t)i * 256 + t] = bf16pair(acc0 * inv + bias[2 * fp],
                                         acc1 * inv + bias[2 * fp + 1]);
}

// ---------------- chunked pooling: block = (chunk, regulon), 8-deep pipeline ----------------
__global__ __launch_bounds__(256) void k_pool(const uint* __restrict__ repu,
                                              const int* __restrict__ boff,
                                              const int* __restrict__ pe_dst,
                                              float* __restrict__ partial) {
    int key = blockIdx.x;            // c * NREG + r (chunk-major dispatch)
    int c = key / NREG;
    int r = key - c * NREG;
    int idx = r * NCHUNK + c;        // boff is regulon-major
    int t = threadIdx.x;
    int lo = boff[idx], hi = boff[idx + 1];
    float acc0 = 0.f, acc1 = 0.f;
    int e = lo;
    for (; e + 8 <= hi; e += 8) {
        int d0 = pe_dst[e+0], d1 = pe_dst[e+1], d2 = pe_dst[e+2], d3 = pe_dst[e+3];
        int d4 = pe_dst[e+4], d5 = pe_dst[e+5], d6 = pe_dst[e+6], d7 = pe_dst[e+7];
        uint v0 = repu[(size_t)d0 * 256 + t];
        uint v1 = repu[(size_t)d1 * 256 + t];
        uint v2 = repu[(size_t)d2 * 256 + t];
        uint v3 = repu[(size_t)d3 * 256 + t];
        uint v4 = repu[(size_t)d4 * 256 + t];
        uint v5 = repu[(size_t)d5 * 256 + t];
        uint v6 = repu[(size_t)d6 * 256 + t];
        uint v7 = repu[(size_t)d7 * 256 + t];
        acc0 += (bf16lo(v0) + bf16lo(v1)) + (bf16lo(v2) + bf16lo(v3))
              + (bf16lo(v4) + bf16lo(v5)) + (bf16lo(v6) + bf16lo(v7));
        acc1 += (bf16hi(v0) + bf16hi(v1)) + (bf16hi(v2) + bf16hi(v3))
              + (bf16hi(v4) + bf16hi(v5)) + (bf16hi(v6) + bf16hi(v7));
    }
    for (; e < hi; ++e) {
        int d = pe_dst[e];
        uint v = repu[(size_t)d * 256 + t];
        acc0 += bf16lo(v);
        acc1 += bf16hi(v);
    }
    float2 o = {acc0, acc1};
    *(float2*)&partial[((size_t)r * NCHUNK + c) * BF + 2 * t] = o;
}

__global__ __launch_bounds__(256) void k_combine(const uint* __restrict__ repu,
                                                 const float* __restrict__ partial,
                                                 float* __restrict__ out) {
    int r = blockIdx.x;
    int t = threadIdx.x;
    int b  = t >> 4;
    int fp = t & 15;
    uint v = repu[(size_t)r * 256 + t];      // self term
    float s0 = bf16lo(v), s1 = bf16hi(v);
    #pragma unroll
    for (int c = 0; c < NCHUNK; ++c) {
        float2 p = *(const float2*)&partial[((size_t)r * NCHUNK + c) * BF + 2 * t];
        s0 += p.x; s1 += p.y;
    }
    float2 o = {s0, s1};
    *(float2*)&out[(size_t)b * NREG * F + r * F + 2 * fp] = o;
}

extern "C" void kernel_launch(void* const* d_in, const int* in_sizes, int n_in,
                              void* d_out, int out_size, void* d_ws, size_t ws_size,
                              hipStream_t stream) {
    const float* x        = (const float*)d_in[0];
    const float* eattr    = (const float*)d_in[1];
    const float* W        = (const float*)d_in[2];
    const float* att_src  = (const float*)d_in[3];
    const float* att_dst  = (const float*)d_in[4];
    const float* lin_edge = (const float*)d_in[5];
    const float* att_edge = (const float*)d_in[6];
    const float* bias     = (const float*)d_in[7];
    const int*   esrc     = (const int*)d_in[8];
    const int*   edst     = (const int*)d_in[9];
    float* out = (float*)d_out;

    char* ws = (char*)d_ws;
    size_t off = 0;
    auto alloc = [&](size_t bytes) -> void* {
        void* p = ws + off;
        off = (off + bytes + 255) & ~(size_t)255;
        return p;
    };
    uint*  hu    = (uint*)alloc((size_t)N * 256 * 4);          // 20.5 MB bf16 h
    uint*  repu  = (uint*)alloc((size_t)N * 256 * 4);          // 20.5 MB bf16 rep
    float* ew    = (float*)alloc((size_t)E * B * 4);           // 41 MB [e][B] c*eattr^T
    float* a_src = (float*)alloc((size_t)N * B * 4);
    float* a_dst = (float*)alloc((size_t)N * B * 4);
    int* dst_off = (int*)alloc((size_t)(N + 1) * 4);
    int* roff    = (int*)alloc((size_t)(NREG + 1) * 4);
    int* csr_src = (int*)alloc((size_t)E * 4);
    int* csr_eid = (int*)alloc((size_t)E * 4);
    int* pe_dst  = (int*)alloc((size_t)E * 4);
    int* boff    = (int*)alloc((size_t)(NREG * NCHUNK + 1) * 4);
    char* zbase   = ws + off;
    int* counts   = (int*)alloc((size_t)N * 4);
    int* cursor   = (int*)alloc((size_t)N * 4);
    float* meanb  = (float*)alloc((size_t)B * 4);
    float* cedge  = (float*)alloc(4);
    size_t zbytes = (size_t)((ws + off) - zbase);
    float* partial = ew;     // alias: ew dead after k_rep; 32.8 MB <= 41 MB

    hipMemsetAsync(zbase, 0, zbytes, stream);

    k_prep1<<<HIST_BLOCKS + 8 + 1, 256, 0, stream>>>(esrc, edst, eattr, lin_edge,
                                                     att_edge, counts, roff,
                                                     meanb, cedge);
    k_scan<<<1, 1024, 0, stream>>>(counts, dst_off, N);
    k_prep2<<<SCAT_BLOCKS + NREG, 256, 0, stream>>>(esrc, edst, dst_off, cursor,
                                                    csr_src, csr_eid,
                                                    roff, boff, pe_dst);
    k_trans<<<E / 256, 256, 0, stream>>>(eattr, cedge, ew);
    k_gemm<<<(B * N) / 256, 256, 0, stream>>>(x, W, att_src, att_dst,
                                              hu, a_src, a_dst);
    k_rep<<<N, 256, 0, stream>>>(hu, a_src, a_dst, ew, csr_eid, bias, meanb,
                                 cedge, dst_off, csr_src, repu);
    k_pool<<<NREG * NCHUNK, 256, 0, stream>>>(repu, boff, pe_dst, partial);
    k_combine<<<NREG, 256, 0, stream>>>(repu, partial, out);
}

// Round 4
// 547.035 us; speedup vs baseline: 1.1219x; 1.0089x over previous
//
#include <hip/hip_runtime.h>
#include <math.h>

#define B    16
#define N    20000
#define E    640000
#define NREG 2000
#define DIN  128
#define F    32
#define NEG  0.2f
#define BF   (B * F)          // 512 floats per node row; 256 uints in bf16
#define NCHUNK 8
#define CS   2500             // nodes per chunk (2500*1KB = 2.44 MB repu slice)
#define HIST_BLOCKS 1024
#define SCAT_BLOCKS 1024

typedef unsigned int uint;

__device__ inline uint bf16pair(float a, float b) {
    uint ua = __float_as_uint(a); ua = (ua + 0x7fffu + ((ua >> 16) & 1u)) >> 16;
    uint ub = __float_as_uint(b); ub = (ub + 0x7fffu + ((ub >> 16) & 1u)) >> 16;
    return ua | (ub << 16);
}
__device__ inline float bf16lo(uint v) { return __uint_as_float(v << 16); }
__device__ inline float bf16hi(uint v) { return __uint_as_float(v & 0xffff0000u); }

// ---------------- prep1: fused  hist+mean | roff | cedge ----------------
__global__ __launch_bounds__(256) void k_prep1(const int* __restrict__ esrc,
                                               const int* __restrict__ edst,
                                               const float* __restrict__ eattr,
                                               const float* __restrict__ lin_edge,
                                               const float* __restrict__ att_edge,
                                               int* __restrict__ counts,
                                               int* __restrict__ roff,
                                               float* __restrict__ meanb,
                                               float* __restrict__ cedge) {
    int blk = blockIdx.x;
    int t = threadIdx.x;
    if (blk < HIST_BLOCKS) {
        // ---- mean partial: batch blk>>6, slice blk&63 (10000 floats contiguous)
        {
            int b = blk >> 6, sl = blk & 63;
            const float4* base = (const float4*)(eattr + (size_t)b * E + sl * 10000);
            float s = 0.f;
            for (int i = t; i < 2500; i += 256) {
                float4 v = base[i];
                s += (v.x + v.y) + (v.z + v.w);
            }
            __shared__ float sh[256];
            sh[t] = s;
            __syncthreads();
            for (int d = 128; d > 0; d >>= 1) {
                if (t < d) sh[t] += sh[t + d];
                __syncthreads();
            }
            if (t == 0) atomicAdd(&meanb[b], sh[0]);
        }
        // ---- histogram
        for (int e = blk * 256 + t; e < E; e += HIST_BLOCKS * 256)
            atomicAdd(&counts[edst[e]], 1);
    } else if (blk < HIST_BLOCKS + 8) {
        int r = (blk - HIST_BLOCKS) * 256 + t;
        if (r > NREG) return;
        int lo = 0, hi = E;
        while (lo < hi) {
            int mid = (lo + hi) >> 1;
            if (esrc[mid] < r) lo = mid + 1; else hi = mid;
        }
        roff[r] = lo;
    } else {
        if (t == 0) {
            float s = 0.f;
            for (int f = 0; f < F; ++f) s += lin_edge[f] * att_edge[f];
            *cedge = s;
        }
    }
}

// ---------------- single-block exclusive scan ----------------
__global__ __launch_bounds__(1024) void k_scan(const int* __restrict__ in,
                                               int* __restrict__ out, int n) {
    __shared__ int sh[1024];
    int t = threadIdx.x;
    int chunk = (n + 1023) / 1024;
    int lo = t * chunk;
    int hi = lo + chunk; if (hi > n) hi = n;
    int local = 0;
    for (int i = lo; i < hi; ++i) local += in[i];
    sh[t] = local;
    __syncthreads();
    for (int d = 1; d < 1024; d <<= 1) {
        int v = (t >= d) ? sh[t - d] : 0;
        __syncthreads();
        sh[t] += v;
        __syncthreads();
    }
    int run = (t == 0) ? 0 : sh[t - 1];
    for (int i = lo; i < hi; ++i) { out[i] = run; run += in[i]; }
    if (t == 1023) out[n] = sh[1023];
}

// ---------------- prep2: fused  scatter | bucket ----------------
__global__ __launch_bounds__(256) void k_prep2(const int* __restrict__ esrc,
                                               const int* __restrict__ edst,
                                               const int* __restrict__ off,
                                               int* __restrict__ cursor,
                                               int* __restrict__ csr_src,
                                               int* __restrict__ csr_eid,
                                               const int* __restrict__ roff,
                                               int* __restrict__ boff,
                                               int* __restrict__ pe_dst) {
    __shared__ int cnt[NCHUNK], pref[NCHUNK], cur[NCHUNK];
    int blk = blockIdx.x;
    int t = threadIdx.x;
    if (blk < SCAT_BLOCKS) {
        int e = blk * 256 + t;
        for (; e < E; e += SCAT_BLOCKS * 256) {
            int d = edst[e];
            int pos = off[d] + atomicAdd(&cursor[d], 1);
            csr_src[pos] = esrc[e];
            csr_eid[pos] = e;
        }
    } else {
        int r = blk - SCAT_BLOCKS;
        int lo = roff[r], hi = roff[r + 1];
        if (t < NCHUNK) { cnt[t] = 0; cur[t] = 0; }
        __syncthreads();
        for (int e = lo + t; e < hi; e += 256)
            atomicAdd(&cnt[edst[e] / CS], 1);
        __syncthreads();
        if (t == 0) {
            int run = 0;
            #pragma unroll
            for (int c = 0; c < NCHUNK; ++c) { pref[c] = run; run += cnt[c]; }
        }
        __syncthreads();
        if (t < NCHUNK) boff[r * NCHUNK + t] = lo + pref[t];
        if (r == 0 && t == 0) boff[NREG * NCHUNK] = E;
        for (int e = lo + t; e < hi; e += 256) {
            int d = edst[e];
            int c = d / CS;
            int pos = lo + pref[c] + atomicAdd(&cur[c], 1);
            pe_dst[pos] = d;
        }
    }
}

// ---------------- coalesced transpose: ew[e][b] = c * eattr[b][e] ----------------
__global__ __launch_bounds__(256) void k_trans(const float* __restrict__ eattr,
                                               const float* __restrict__ cedge,
                                               float* __restrict__ ew) {
    __shared__ float tile[256][17];
    int e0 = blockIdx.x * 256;
    int t = threadIdx.x;
    #pragma unroll
    for (int b = 0; b < B; ++b)
        tile[t][b] = eattr[(size_t)b * E + e0 + t];
    __syncthreads();
    float c = *cedge;
    #pragma unroll
    for (int p = 0; p < 4; ++p) {
        int i4 = (p * 256 + t) * 4;
        int el = i4 >> 4, b0 = i4 & 15;
        float4 o;
        o.x = c * tile[el][b0 + 0];
        o.y = c * tile[el][b0 + 1];
        o.z = c * tile[el][b0 + 2];
        o.w = c * tile[el][b0 + 3];
        *(float4*)&ew[(size_t)e0 * 16 + i4] = o;
    }
}

// ---------------- h = x @ W -> bf16 [n][B][F]; fused a_src/a_dst ----------------
#define XS_LD 260
__global__ __launch_bounds__(256) void k_gemm(const float* __restrict__ x,
                                              const float* __restrict__ W,
                                              const float* __restrict__ att_src,
                                              const float* __restrict__ att_dst,
                                              uint* __restrict__ hu,
                                              float* __restrict__ a_src,
                                              float* __restrict__ a_dst) {
    __shared__ float Ws[DIN * F];
    __shared__ float xs[32 * XS_LD];
    int t = threadIdx.x;
    int row0 = blockIdx.x * 256;      // flattened b*N + n
    #pragma unroll
    for (int j = 0; j < 4; ++j) {
        int idx = (t + 256 * j) * 4;
        *(float4*)&Ws[idx] = *(const float4*)&W[idx];
    }
    const int lr = t & 63;
    const int fg = t >> 6;            // wave-uniform
    float acc[4][8];
    #pragma unroll
    for (int i = 0; i < 4; ++i)
        #pragma unroll
        for (int j = 0; j < 8; ++j) acc[i][j] = 0.f;

    for (int kc = 0; kc < 4; ++kc) {
        __syncthreads();
        #pragma unroll
        for (int j = 0; j < 8; ++j) {
            int p = t + 256 * j;
            int row = p >> 3;
            int kk  = (p & 7) * 4;
            float4 g = *(const float4*)&x[(size_t)(row0 + row) * DIN + kc * 32 + kk];
            xs[(kk + 0) * XS_LD + row] = g.x;
            xs[(kk + 1) * XS_LD + row] = g.y;
            xs[(kk + 2) * XS_LD + row] = g.z;
            xs[(kk + 3) * XS_LD + row] = g.w;
        }
        __syncthreads();
        #pragma unroll
        for (int k = 0; k < 32; ++k) {
            float4 xv = *(float4*)&xs[k * XS_LD + 4 * lr];
            float4 w0 = *(float4*)&Ws[(kc * 32 + k) * F + fg * 8];
            float4 w1 = *(float4*)&Ws[(kc * 32 + k) * F + fg * 8 + 4];
            float xr[4] = {xv.x, xv.y, xv.z, xv.w};
            float wr[8] = {w0.x, w0.y, w0.z, w0.w, w1.x, w1.y, w1.z, w1.w};
            #pragma unroll
            for (int i = 0; i < 4; ++i)
                #pragma unroll
                for (int j = 0; j < 8; ++j)
                    acc[i][j] = fmaf(xr[i], wr[j], acc[i][j]);
        }
    }
    #pragma unroll
    for (int i = 0; i < 4; ++i) {
        int row = row0 + lr * 4 + i;
        int b = row / N;
        int n = row - b * N;
        uint4 o;
        o.x = bf16pair(acc[i][0], acc[i][1]);
        o.y = bf16pair(acc[i][2], acc[i][3]);
        o.z = bf16pair(acc[i][4], acc[i][5]);
        o.w = bf16pair(acc[i][6], acc[i][7]);
        *(uint4*)&hu[(size_t)n * 256 + b * 16 + fg * 4] = o;
    }
    float* red = xs;
    __syncthreads();
    #pragma unroll
    for (int i = 0; i < 4; ++i) {
        float s1 = 0.f, s2 = 0.f;
        #pragma unroll
        for (int j = 0; j < 8; ++j) {
            float as = att_src[fg * 8 + j];
            float ad = att_dst[fg * 8 + j];
            s1 = fmaf(acc[i][j], as, s1);
            s2 = fmaf(acc[i][j], ad, s2);
        }
        red[fg * 256 + lr * 4 + i]        = s1;
        red[1024 + fg * 256 + lr * 4 + i] = s2;
    }
    __syncthreads();
    {
        float s1 = red[t] + red[256 + t] + red[512 + t] + red[768 + t];
        float s2 = red[1024 + t] + red[1280 + t] + red[1536 + t] + red[1792 + t];
        int row = row0 + t;
        int b = row / N;
        int n = row - b * N;
        a_src[(size_t)n * B + b] = s1;
        a_dst[(size_t)n * B + b] = s2;
    }
}

// ---------------- rep: shuffle-shared alpha/exp (1 exp per edge per b-group),
//                  per-thread work = hu gather + 2 fmaf only ----------------
__global__ __launch_bounds__(256) void k_rep(
    const uint* __restrict__ hu, const float* __restrict__ a_src,
    const float* __restrict__ a_dst, const float* __restrict__ ew,
    const int* __restrict__ csr_eid,
    const float* __restrict__ bias, const float* __restrict__ meanb,
    const float* __restrict__ cedge, const int* __restrict__ dst_off,
    const int* __restrict__ csr_src, uint* __restrict__ repu) {
    int i = blockIdx.x;
    int t = threadIdx.x;
    int b  = t >> 4;
    int fp = t & 15;
    float c = *cedge;
    float adst = a_dst[(size_t)i * B + b];
    float meanv = meanb[b] * (1.f / (float)E);
    // self-loop term (identical across the 16-lane fp group)
    float al = a_src[(size_t)i * B + b] + adst + meanv * c;
    al = al > 0.f ? al : NEG * al;
    float wself = __expf(al);
    uint hv = hu[(size_t)i * 256 + t];
    float acc0 = wself * bf16lo(hv);
    float acc1 = wself * bf16hi(hv);
    float ssum = 0.f;                 // per-lane partial of edge weights
    int lo = dst_off[i], hi = dst_off[i + 1];
    for (int j = lo; j < hi; j += 16) {
        int jj = j + fp;
        int idx = jj < hi ? jj : hi - 1;          // clamped (hi>lo inside loop)
        int   sv_l = csr_src[idx];
        int   ev_l = csr_eid[idx];
        float a2 = a_src[(size_t)sv_l * B + b] + adst
                 + ew[(size_t)ev_l * B + b];
        a2 = a2 > 0.f ? a2 : NEG * a2;
        float w_l = (jj < hi) ? __expf(a2) : 0.f; // dead lanes contribute 0
        ssum += w_l;
        #pragma unroll
        for (int q = 0; q < 16; ++q) {
            float wq = __shfl(w_l, q, 16);        // same-b 16-lane group
            int   sq = __shfl(sv_l, q, 16);
            uint v = hu[(size_t)sq * 256 + t];
            acc0 = fmaf(wq, bf16lo(v), acc0);
            acc1 = fmaf(wq, bf16hi(v), acc1);
        }
    }
    // softmax denominator: reduce partials across the 16-lane fp group
    #pragma unroll
    for (int d = 1; d < 16; d <<= 1) ssum += __shfl_xor(ssum, d, 16);
    float inv = 1.f / (wself + ssum);
    repu[(size_t)i * 256 + t] = bf16pair(acc0 * inv + bias[2 * fp],
                                         acc1 * inv + bias[2 * fp + 1]);
}

// ---------------- chunked pooling: block = (chunk, regulon), 8-deep pipeline ----------------
__global__ __launch_bounds__(256) void k_pool(const uint* __restrict__ repu,
                                              const int* __restrict__ boff,
                                              const int* __restrict__ pe_dst,
                                              float* __restrict__ partial) {
    int key = blockIdx.x;            // c * NREG + r (chunk-major dispatch)
    int c = key / NREG;
    int r = key - c * NREG;
    int idx = r * NCHUNK + c;        // boff is regulon-major
    int t = threadIdx.x;
    int lo = boff[idx], hi = boff[idx + 1];
    float acc0 = 0.f, acc1 = 0.f;
    int e = lo;
    for (; e + 8 <= hi; e += 8) {
        int d0 = pe_dst[e+0], d1 = pe_dst[e+1], d2 = pe_dst[e+2], d3 = pe_dst[e+3];
        int d4 = pe_dst[e+4], d5 = pe_dst[e+5], d6 = pe_dst[e+6], d7 = pe_dst[e+7];
        uint v0 = repu[(size_t)d0 * 256 + t];
        uint v1 = repu[(size_t)d1 * 256 + t];
        uint v2 = repu[(size_t)d2 * 256 + t];
        uint v3 = repu[(size_t)d3 * 256 + t];
        uint v4 = repu[(size_t)d4 * 256 + t];
        uint v5 = repu[(size_t)d5 * 256 + t];
        uint v6 = repu[(size_t)d6 * 256 + t];
        uint v7 = repu[(size_t)d7 * 256 + t];
        acc0 += (bf16lo(v0) + bf16lo(v1)) + (bf16lo(v2) + bf16lo(v3))
              + (bf16lo(v4) + bf16lo(v5)) + (bf16lo(v6) + bf16lo(v7));
        acc1 += (bf16hi(v0) + bf16hi(v1)) + (bf16hi(v2) + bf16hi(v3))
              + (bf16hi(v4) + bf16hi(v5)) + (bf16hi(v6) + bf16hi(v7));
    }
    for (; e < hi; ++e) {
        int d = pe_dst[e];
        uint v = repu[(size_t)d * 256 + t];
        acc0 += bf16lo(v);
        acc1 += bf16hi(v);
    }
    float2 o = {acc0, acc1};
    *(float2*)&partial[((size_t)r * NCHUNK + c) * BF + 2 * t] = o;
}

__global__ __launch_bounds__(256) void k_combine(const uint* __restrict__ repu,
                                                 const float* __restrict__ partial,
                                                 float* __restrict__ out) {
    int r = blockIdx.x;
    int t = threadIdx.x;
    int b  = t >> 4;
    int fp = t & 15;
    uint v = repu[(size_t)r * 256 + t];      // self term
    float s0 = bf16lo(v), s1 = bf16hi(v);
    #pragma unroll
    for (int c = 0; c < NCHUNK; ++c) {
        float2 p = *(const float2*)&partial[((size_t)r * NCHUNK + c) * BF + 2 * t];
        s0 += p.x; s1 += p.y;
    }
    float2 o = {s0, s1};
    *(float2*)&out[(size_t)b * NREG * F + r * F + 2 * fp] = o;
}

extern "C" void kernel_launch(void* const* d_in, const int* in_sizes, int n_in,
                              void* d_out, int out_size, void* d_ws, size_t ws_size,
                              hipStream_t stream) {
    const float* x        = (const float*)d_in[0];
    const float* eattr    = (const float*)d_in[1];
    const float* W        = (const float*)d_in[2];
    const float* att_src  = (const float*)d_in[3];
    const float* att_dst  = (const float*)d_in[4];
    const float* lin_edge = (const float*)d_in[5];
    const float* att_edge = (const float*)d_in[6];
    const float* bias     = (const float*)d_in[7];
    const int*   esrc     = (const int*)d_in[8];
    const int*   edst     = (const int*)d_in[9];
    float* out = (float*)d_out;

    char* ws = (char*)d_ws;
    size_t off = 0;
    auto alloc = [&](size_t bytes) -> void* {
        void* p = ws + off;
        off = (off + bytes + 255) & ~(size_t)255;
        return p;
    };
    uint*  hu    = (uint*)alloc((size_t)N * 256 * 4);          // 20.5 MB bf16 h
    uint*  repu  = (uint*)alloc((size_t)N * 256 * 4);          // 20.5 MB bf16 rep
    float* ew    = (float*)alloc((size_t)E * B * 4);           // 41 MB [e][B] c*eattr^T
    float* a_src = (float*)alloc((size_t)N * B * 4);
    float* a_dst = (float*)alloc((size_t)N * B * 4);
    int* dst_off = (int*)alloc((size_t)(N + 1) * 4);
    int* roff    = (int*)alloc((size_t)(NREG + 1) * 4);
    int* csr_src = (int*)alloc((size_t)E * 4);
    int* csr_eid = (int*)alloc((size_t)E * 4);
    int* pe_dst  = (int*)alloc((size_t)E * 4);
    int* boff    = (int*)alloc((size_t)(NREG * NCHUNK + 1) * 4);
    char* zbase   = ws + off;
    int* counts   = (int*)alloc((size_t)N * 4);
    int* cursor   = (int*)alloc((size_t)N * 4);
    float* meanb  = (float*)alloc((size_t)B * 4);
    float* cedge  = (float*)alloc(4);
    size_t zbytes = (size_t)((ws + off) - zbase);
    float* partial = ew;     // alias: ew dead after k_rep; 32.8 MB <= 41 MB

    hipMemsetAsync(zbase, 0, zbytes, stream);

    k_prep1<<<HIST_BLOCKS + 8 + 1, 256, 0, stream>>>(esrc, edst, eattr, lin_edge,
                                                     att_edge, counts, roff,
                                                     meanb, cedge);
    k_scan<<<1, 1024, 0, stream>>>(counts, dst_off, N);
    k_prep2<<<SCAT_BLOCKS + NREG, 256, 0, stream>>>(esrc, edst, dst_off, cursor,
                                                    csr_src, csr_eid,
                                                    roff, boff, pe_dst);
    k_trans<<<E / 256, 256, 0, stream>>>(eattr, cedge, ew);
    k_gemm<<<(B * N) / 256, 256, 0, stream>>>(x, W, att_src, att_dst,
                                              hu, a_src, a_dst);
    k_rep<<<N, 256, 0, stream>>>(hu, a_src, a_dst, ew, csr_eid, bias, meanb,
                                 cedge, dst_off, csr_src, repu);
    k_pool<<<NREG * NCHUNK, 256, 0, stream>>>(repu, boff, pe_dst, partial);
    k_combine<<<NREG, 256, 0, stream>>>(repu, partial, out);
}

// Round 5
// 546.595 us; speedup vs baseline: 1.1228x; 1.0008x over previous
//
#include <hip/hip_runtime.h>
#include <math.h>

#define B    16
#define N    20000
#define E    640000
#define NREG 2000
#define DIN  128
#define F    32
#define NEG  0.2f
#define BF   (B * F)          // 512 floats per node row; 256 uints in bf16
#define NCHUNK 8
#define CS   2500             // nodes per chunk (2500*1KB = 2.44 MB repu slice)
#define HIST_BLOCKS 1024
#define SCAT_BLOCKS 1024

typedef unsigned int uint;

__device__ inline uint bf16pair(float a, float b) {
    uint ua = __float_as_uint(a); ua = (ua + 0x7fffu + ((ua >> 16) & 1u)) >> 16;
    uint ub = __float_as_uint(b); ub = (ub + 0x7fffu + ((ub >> 16) & 1u)) >> 16;
    return ua | (ub << 16);
}
__device__ inline float bf16lo(uint v) { return __uint_as_float(v << 16); }
__device__ inline float bf16hi(uint v) { return __uint_as_float(v & 0xffff0000u); }

// ---------------- prep1: fused  hist+mean | roff | cedge ----------------
__global__ __launch_bounds__(256) void k_prep1(const int* __restrict__ esrc,
                                               const int* __restrict__ edst,
                                               const float* __restrict__ eattr,
                                               const float* __restrict__ lin_edge,
                                               const float* __restrict__ att_edge,
                                               int* __restrict__ counts,
                                               int* __restrict__ roff,
                                               float* __restrict__ meanb,
                                               float* __restrict__ cedge) {
    int blk = blockIdx.x;
    int t = threadIdx.x;
    if (blk < HIST_BLOCKS) {
        // ---- mean partial: batch blk>>6, slice blk&63 (10000 floats contiguous)
        {
            int b = blk >> 6, sl = blk & 63;
            const float4* base = (const float4*)(eattr + (size_t)b * E + sl * 10000);
            float s = 0.f;
            for (int i = t; i < 2500; i += 256) {
                float4 v = base[i];
                s += (v.x + v.y) + (v.z + v.w);
            }
            __shared__ float sh[256];
            sh[t] = s;
            __syncthreads();
            for (int d = 128; d > 0; d >>= 1) {
                if (t < d) sh[t] += sh[t + d];
                __syncthreads();
            }
            if (t == 0) atomicAdd(&meanb[b], sh[0]);
        }
        // ---- histogram
        for (int e = blk * 256 + t; e < E; e += HIST_BLOCKS * 256)
            atomicAdd(&counts[edst[e]], 1);
    } else if (blk < HIST_BLOCKS + 8) {
        int r = (blk - HIST_BLOCKS) * 256 + t;
        if (r > NREG) return;
        int lo = 0, hi = E;
        while (lo < hi) {
            int mid = (lo + hi) >> 1;
            if (esrc[mid] < r) lo = mid + 1; else hi = mid;
        }
        roff[r] = lo;
    } else {
        if (t == 0) {
            float s = 0.f;
            for (int f = 0; f < F; ++f) s += lin_edge[f] * att_edge[f];
            *cedge = s;
        }
    }
}

// ---------------- single-block exclusive scan ----------------
__global__ __launch_bounds__(1024) void k_scan(const int* __restrict__ in,
                                               int* __restrict__ out, int n) {
    __shared__ int sh[1024];
    int t = threadIdx.x;
    int chunk = (n + 1023) / 1024;
    int lo = t * chunk;
    int hi = lo + chunk; if (hi > n) hi = n;
    int local = 0;
    for (int i = lo; i < hi; ++i) local += in[i];
    sh[t] = local;
    __syncthreads();
    for (int d = 1; d < 1024; d <<= 1) {
        int v = (t >= d) ? sh[t - d] : 0;
        __syncthreads();
        sh[t] += v;
        __syncthreads();
    }
    int run = (t == 0) ? 0 : sh[t - 1];
    for (int i = lo; i < hi; ++i) { out[i] = run; run += in[i]; }
    if (t == 1023) out[n] = sh[1023];
}

// ---------------- prep2: fused  scatter | bucket ----------------
// csr_se[pos] = {src_node, edge_id}  (packed: one 8B scatter, one load in k_rep)
__global__ __launch_bounds__(256) void k_prep2(const int* __restrict__ esrc,
                                               const int* __restrict__ edst,
                                               const int* __restrict__ off,
                                               int* __restrict__ cursor,
                                               int2* __restrict__ csr_se,
                                               const int* __restrict__ roff,
                                               int* __restrict__ boff,
                                               int* __restrict__ pe_dst) {
    __shared__ int cnt[NCHUNK], pref[NCHUNK], cur[NCHUNK];
    int blk = blockIdx.x;
    int t = threadIdx.x;
    if (blk < SCAT_BLOCKS) {
        int e = blk * 256 + t;
        for (; e < E; e += SCAT_BLOCKS * 256) {
            int d = edst[e];
            int pos = off[d] + atomicAdd(&cursor[d], 1);
            csr_se[pos] = make_int2(esrc[e], e);
        }
    } else {
        int r = blk - SCAT_BLOCKS;
        int lo = roff[r], hi = roff[r + 1];
        if (t < NCHUNK) { cnt[t] = 0; cur[t] = 0; }
        __syncthreads();
        for (int e = lo + t; e < hi; e += 256)
            atomicAdd(&cnt[edst[e] / CS], 1);
        __syncthreads();
        if (t == 0) {
            int run = 0;
            #pragma unroll
            for (int c = 0; c < NCHUNK; ++c) { pref[c] = run; run += cnt[c]; }
        }
        __syncthreads();
        if (t < NCHUNK) boff[r * NCHUNK + t] = lo + pref[t];
        if (r == 0 && t == 0) boff[NREG * NCHUNK] = E;
        for (int e = lo + t; e < hi; e += 256) {
            int d = edst[e];
            int c = d / CS;
            int pos = lo + pref[c] + atomicAdd(&cur[c], 1);
            pe_dst[pos] = d;
        }
    }
}

// ---------------- coalesced transpose: ew[e][b] = c * eattr[b][e] ----------------
// launched right before k_rep so ew is L2/L3-hot for its random reads
__global__ __launch_bounds__(256) void k_trans(const float* __restrict__ eattr,
                                               const float* __restrict__ cedge,
                                               float* __restrict__ ew) {
    __shared__ float tile[256][17];
    int e0 = blockIdx.x * 256;
    int t = threadIdx.x;
    #pragma unroll
    for (int b = 0; b < B; ++b)
        tile[t][b] = eattr[(size_t)b * E + e0 + t];
    __syncthreads();
    float c = *cedge;
    #pragma unroll
    for (int p = 0; p < 4; ++p) {
        int i4 = (p * 256 + t) * 4;
        int el = i4 >> 4, b0 = i4 & 15;
        float4 o;
        o.x = c * tile[el][b0 + 0];
        o.y = c * tile[el][b0 + 1];
        o.z = c * tile[el][b0 + 2];
        o.w = c * tile[el][b0 + 3];
        *(float4*)&ew[(size_t)e0 * 16 + i4] = o;
    }
}

// ---------------- h = x @ W -> bf16 [n][B][F]; fused a_src/a_dst ----------------
#define XS_LD 260
__global__ __launch_bounds__(256) void k_gemm(const float* __restrict__ x,
                                              const float* __restrict__ W,
                                              const float* __restrict__ att_src,
                                              const float* __restrict__ att_dst,
                                              uint* __restrict__ hu,
                                              float* __restrict__ a_src,
                                              float* __restrict__ a_dst) {
    __shared__ float Ws[DIN * F];
    __shared__ float xs[32 * XS_LD];
    int t = threadIdx.x;
    int row0 = blockIdx.x * 256;      // flattened b*N + n
    #pragma unroll
    for (int j = 0; j < 4; ++j) {
        int idx = (t + 256 * j) * 4;
        *(float4*)&Ws[idx] = *(const float4*)&W[idx];
    }
    const int lr = t & 63;
    const int fg = t >> 6;            // wave-uniform
    float acc[4][8];
    #pragma unroll
    for (int i = 0; i < 4; ++i)
        #pragma unroll
        for (int j = 0; j < 8; ++j) acc[i][j] = 0.f;

    for (int kc = 0; kc < 4; ++kc) {
        __syncthreads();
        #pragma unroll
        for (int j = 0; j < 8; ++j) {
            int p = t + 256 * j;
            int row = p >> 3;
            int kk  = (p & 7) * 4;
            float4 g = *(const float4*)&x[(size_t)(row0 + row) * DIN + kc * 32 + kk];
            xs[(kk + 0) * XS_LD + row] = g.x;
            xs[(kk + 1) * XS_LD + row] = g.y;
            xs[(kk + 2) * XS_LD + row] = g.z;
            xs[(kk + 3) * XS_LD + row] = g.w;
        }
        __syncthreads();
        #pragma unroll
        for (int k = 0; k < 32; ++k) {
            float4 xv = *(float4*)&xs[k * XS_LD + 4 * lr];
            float4 w0 = *(float4*)&Ws[(kc * 32 + k) * F + fg * 8];
            float4 w1 = *(float4*)&Ws[(kc * 32 + k) * F + fg * 8 + 4];
            float xr[4] = {xv.x, xv.y, xv.z, xv.w};
            float wr[8] = {w0.x, w0.y, w0.z, w0.w, w1.x, w1.y, w1.z, w1.w};
            #pragma unroll
            for (int i = 0; i < 4; ++i)
                #pragma unroll
                for (int j = 0; j < 8; ++j)
                    acc[i][j] = fmaf(xr[i], wr[j], acc[i][j]);
        }
    }
    #pragma unroll
    for (int i = 0; i < 4; ++i) {
        int row = row0 + lr * 4 + i;
        int b = row / N;
        int n = row - b * N;
        uint4 o;
        o.x = bf16pair(acc[i][0], acc[i][1]);
        o.y = bf16pair(acc[i][2], acc[i][3]);
        o.z = bf16pair(acc[i][4], acc[i][5]);
        o.w = bf16pair(acc[i][6], acc[i][7]);
        *(uint4*)&hu[(size_t)n * 256 + b * 16 + fg * 4] = o;
    }
    float* red = xs;
    __syncthreads();
    #pragma unroll
    for (int i = 0; i < 4; ++i) {
        float s1 = 0.f, s2 = 0.f;
        #pragma unroll
        for (int j = 0; j < 8; ++j) {
            float as = att_src[fg * 8 + j];
            float ad = att_dst[fg * 8 + j];
            s1 = fmaf(acc[i][j], as, s1);
            s2 = fmaf(acc[i][j], ad, s2);
        }
        red[fg * 256 + lr * 4 + i]        = s1;
        red[1024 + fg * 256 + lr * 4 + i] = s2;
    }
    __syncthreads();
    {
        float s1 = red[t] + red[256 + t] + red[512 + t] + red[768 + t];
        float s2 = red[1024 + t] + red[1280 + t] + red[1536 + t] + red[1792 + t];
        int row = row0 + t;
        int b = row / N;
        int n = row - b * N;
        a_src[(size_t)n * B + b] = s1;
        a_dst[(size_t)n * B + b] = s2;
    }
}

// ---------------- rep: two-phase LDS-shared weights, dwordx2 row gathers ----
// phase A: thread (edge fpA, batch bA) computes ONE w, writes {w,sv} to LDS
// phase B: thread (epar, b4, u) processes 8 edges: ds_read_b64 + dwordx2 + 4 fmaf
__global__ __launch_bounds__(256) void k_rep(
    const uint* __restrict__ hu, const float* __restrict__ a_src,
    const float* __restrict__ a_dst, const float* __restrict__ ew,
    const int2* __restrict__ csr_se,
    const float* __restrict__ bias, const float* __restrict__ meanb,
    const float* __restrict__ cedge, const int* __restrict__ dst_off,
    uint* __restrict__ repu) {
    __shared__ uint2 wsh[2][4][64];   // [buf][wave][edge*4 + b4] = {w_bits, sv}
    int i = blockIdx.x;
    int t = threadIdx.x;
    int w = t >> 6;
    int l = t & 63;
    // phase-A identity: edge-in-tile, batch
    int fpA = l & 15;
    int bA  = (w << 2) + (l >> 4);
    // phase-B identity: edge parity, batch, uint2-slot
    int epar = l >> 5;
    int b4   = (l >> 3) & 3;
    int bB   = (w << 2) + b4;
    int u    = l & 7;
    int laneoff = bB * 8 + u;                 // uint2 index within a 128-uint2 row

    float c = *cedge;
    int lo = dst_off[i], hi = dst_off[i + 1];
    float adstA = a_dst[i * B + bA];
    float ssum = 0.f;
    float acc0 = 0.f, acc1 = 0.f, acc2 = 0.f, acc3 = 0.f;
    const uint2* hu2 = (const uint2*)hu;

    int nt = 0;
    for (int j = lo; j < hi; j += 16, ++nt) {
        int p = nt & 1;
        // ---- phase A: one weight per thread
        int jj = j + fpA;
        int idx = jj < hi ? jj : hi - 1;
        int2 se = csr_se[idx];
        float a2 = a_src[se.x * B + bA] + adstA + ew[se.y * B + bA];
        a2 = a2 > 0.f ? a2 : NEG * a2;
        float wv = (jj < hi) ? __expf(a2) : 0.f;
        ssum += wv;
        wsh[p][w][fpA * 4 + (l >> 4)] = make_uint2(__float_as_uint(wv), (uint)se.x);
        __syncthreads();
        // ---- phase B: 8 edges of this parity, 4 f-values each
        #pragma unroll
        for (int k = 0; k < 8; ++k) {
            uint2 ws = wsh[p][w][(2 * k + epar) * 4 + b4];
            float wq = __uint_as_float(ws.x);
            uint2 v = hu2[(int)ws.y * 128 + laneoff];
            acc0 = fmaf(wq, bf16lo(v.x), acc0);
            acc1 = fmaf(wq, bf16hi(v.x), acc1);
            acc2 = fmaf(wq, bf16lo(v.y), acc2);
            acc3 = fmaf(wq, bf16hi(v.y), acc3);
        }
    }
    // denominator: reduce over the 16 fpA lanes (same bA), then redistribute to bB
    #pragma unroll
    for (int d = 1; d < 16; d <<= 1) ssum += __shfl_xor(ssum, d, 16);
    float Sb = __shfl(ssum, b4 << 4, 64);     // value held by lanes with bA==bB
    // self-loop term (epar 0 only, to avoid double count across parity merge)
    float meanv = meanb[bB] * (1.f / (float)E);
    float al = a_src[i * B + bB] + a_dst[i * B + bB] + meanv * c;
    al = al > 0.f ? al : NEG * al;
    float wself = __expf(al);
    if (epar == 0) {
        uint2 hv = hu2[i * 128 + laneoff];
        acc0 = fmaf(wself, bf16lo(hv.x), acc0);
        acc1 = fmaf(wself, bf16hi(hv.x), acc1);
        acc2 = fmaf(wself, bf16lo(hv.y), acc2);
        acc3 = fmaf(wself, bf16hi(hv.y), acc3);
    }
    // merge parity halves
    acc0 += __shfl_xor(acc0, 32, 64);
    acc1 += __shfl_xor(acc1, 32, 64);
    acc2 += __shfl_xor(acc2, 32, 64);
    acc3 += __shfl_xor(acc3, 32, 64);
    if (epar == 0) {
        float inv = 1.f / (wself + Sb);
        uint2 o;
        o.x = bf16pair(acc0 * inv + bias[4 * u + 0], acc1 * inv + bias[4 * u + 1]);
        o.y = bf16pair(acc2 * inv + bias[4 * u + 2], acc3 * inv + bias[4 * u + 3]);
        ((uint2*)repu)[i * 128 + laneoff] = o;
    }
}

// ---------------- chunked pooling: block = (chunk, regulon), 8-deep pipeline ----------------
__global__ __launch_bounds__(256) void k_pool(const uint* __restrict__ repu,
                                              const int* __restrict__ boff,
                                              const int* __restrict__ pe_dst,
                                              float* __restrict__ partial) {
    int key = blockIdx.x;            // c * NREG + r (chunk-major dispatch)
    int c = key / NREG;
    int r = key - c * NREG;
    int idx = r * NCHUNK + c;        // boff is regulon-major
    int t = threadIdx.x;
    int lo = boff[idx], hi = boff[idx + 1];
    float acc0 = 0.f, acc1 = 0.f;
    int e = lo;
    for (; e + 8 <= hi; e += 8) {
        int d0 = pe_dst[e+0], d1 = pe_dst[e+1], d2 = pe_dst[e+2], d3 = pe_dst[e+3];
        int d4 = pe_dst[e+4], d5 = pe_dst[e+5], d6 = pe_dst[e+6], d7 = pe_dst[e+7];
        uint v0 = repu[(size_t)d0 * 256 + t];
        uint v1 = repu[(size_t)d1 * 256 + t];
        uint v2 = repu[(size_t)d2 * 256 + t];
        uint v3 = repu[(size_t)d3 * 256 + t];
        uint v4 = repu[(size_t)d4 * 256 + t];
        uint v5 = repu[(size_t)d5 * 256 + t];
        uint v6 = repu[(size_t)d6 * 256 + t];
        uint v7 = repu[(size_t)d7 * 256 + t];
        acc0 += (bf16lo(v0) + bf16lo(v1)) + (bf16lo(v2) + bf16lo(v3))
              + (bf16lo(v4) + bf16lo(v5)) + (bf16lo(v6) + bf16lo(v7));
        acc1 += (bf16hi(v0) + bf16hi(v1)) + (bf16hi(v2) + bf16hi(v3))
              + (bf16hi(v4) + bf16hi(v5)) + (bf16hi(v6) + bf16hi(v7));
    }
    for (; e < hi; ++e) {
        int d = pe_dst[e];
        uint v = repu[(size_t)d * 256 + t];
        acc0 += bf16lo(v);
        acc1 += bf16hi(v);
    }
    float2 o = {acc0, acc1};
    *(float2*)&partial[((size_t)r * NCHUNK + c) * BF + 2 * t] = o;
}

__global__ __launch_bounds__(256) void k_combine(const uint* __restrict__ repu,
                                                 const float* __restrict__ partial,
                                                 float* __restrict__ out) {
    int r = blockIdx.x;
    int t = threadIdx.x;
    int b  = t >> 4;
    int fp = t & 15;
    uint v = repu[(size_t)r * 256 + t];      // self term
    float s0 = bf16lo(v), s1 = bf16hi(v);
    #pragma unroll
    for (int c = 0; c < NCHUNK; ++c) {
        float2 p = *(const float2*)&partial[((size_t)r * NCHUNK + c) * BF + 2 * t];
        s0 += p.x; s1 += p.y;
    }
    float2 o = {s0, s1};
    *(float2*)&out[(size_t)b * NREG * F + r * F + 2 * fp] = o;
}

extern "C" void kernel_launch(void* const* d_in, const int* in_sizes, int n_in,
                              void* d_out, int out_size, void* d_ws, size_t ws_size,
                              hipStream_t stream) {
    const float* x        = (const float*)d_in[0];
    const float* eattr    = (const float*)d_in[1];
    const float* W        = (const float*)d_in[2];
    const float* att_src  = (const float*)d_in[3];
    const float* att_dst  = (const float*)d_in[4];
    const float* lin_edge = (const float*)d_in[5];
    const float* att_edge = (const float*)d_in[6];
    const float* bias     = (const float*)d_in[7];
    const int*   esrc     = (const int*)d_in[8];
    const int*   edst     = (const int*)d_in[9];
    float* out = (float*)d_out;

    char* ws = (char*)d_ws;
    size_t off = 0;
    auto alloc = [&](size_t bytes) -> void* {
        void* p = ws + off;
        off = (off + bytes + 255) & ~(size_t)255;
        return p;
    };
    uint*  hu    = (uint*)alloc((size_t)N * 256 * 4);          // 20.5 MB bf16 h
    uint*  repu  = (uint*)alloc((size_t)N * 256 * 4);          // 20.5 MB bf16 rep
    float* ew    = (float*)alloc((size_t)E * B * 4);           // 41 MB [e][B] c*eattr^T
    float* a_src = (float*)alloc((size_t)N * B * 4);
    float* a_dst = (float*)alloc((size_t)N * B * 4);
    int* dst_off = (int*)alloc((size_t)(N + 1) * 4);
    int* roff    = (int*)alloc((size_t)(NREG + 1) * 4);
    int2* csr_se = (int2*)alloc((size_t)E * 8);
    int* pe_dst  = (int*)alloc((size_t)E * 4);
    int* boff    = (int*)alloc((size_t)(NREG * NCHUNK + 1) * 4);
    char* zbase   = ws + off;
    int* counts   = (int*)alloc((size_t)N * 4);
    int* cursor   = (int*)alloc((size_t)N * 4);
    float* meanb  = (float*)alloc((size_t)B * 4);
    float* cedge  = (float*)alloc(4);
    size_t zbytes = (size_t)((ws + off) - zbase);
    float* partial = ew;     // alias: ew dead after k_rep; 32.8 MB <= 41 MB

    hipMemsetAsync(zbase, 0, zbytes, stream);

    k_prep1<<<HIST_BLOCKS + 8 + 1, 256, 0, stream>>>(esrc, edst, eattr, lin_edge,
                                                     att_edge, counts, roff,
                                                     meanb, cedge);
    k_scan<<<1, 1024, 0, stream>>>(counts, dst_off, N);
    k_prep2<<<SCAT_BLOCKS + NREG, 256, 0, stream>>>(esrc, edst, dst_off, cursor,
                                                    csr_se, roff, boff, pe_dst);
    // gemm BEFORE trans: its 164 MB x-stream must not evict ew between
    // k_trans's write and k_rep's random read (round-4 lesson: 69 MB HBM refetch)
    k_gemm<<<(B * N) / 256, 256, 0, stream>>>(x, W, att_src, att_dst,
                                              hu, a_src, a_dst);
    k_trans<<<E / 256, 256, 0, stream>>>(eattr, cedge, ew);
    k_rep<<<N, 256, 0, stream>>>(hu, a_src, a_dst, ew, csr_se, bias, meanb,
                                 cedge, dst_off, repu);
    k_pool<<<NREG * NCHUNK, 256, 0, stream>>>(repu, boff, pe_dst, partial);
    k_combine<<<NREG, 256, 0, stream>>>(repu, partial, out);
}

// Round 7
// 488.979 us; speedup vs baseline: 1.2551x; 1.1178x over previous
//
#include <hip/hip_runtime.h>
#include <hip/hip_fp16.h>
#include <math.h>

#define B    16
#define N    20000
#define E    640000
#define NREG 2000
#define DIN  128
#define F    32
#define NEG  0.2f
#define BF   (B * F)          // 512 values per node row; f16 = 1KB
#define NCHUNK 8
#define CS   2500             // nodes per chunk (2500*1KB = 2.44 MB repu slice)
#define HIST_BLOCKS 1024
#define SCAT_BLOCKS 1024

typedef unsigned int uint;

__device__ inline uint f16pair(float a, float b) {
    __half2 h = __floats2half2_rn(a, b);
    return *(uint*)&h;
}
__device__ inline float2 h2f2(uint v) {
    return __half22float2(*(__half2*)&v);
}

// ---------------- prep1: fused  hist+mean | roff | cedge ----------------
__global__ __launch_bounds__(256) void k_prep1(const int* __restrict__ esrc,
                                               const int* __restrict__ edst,
                                               const float* __restrict__ eattr,
                                               const float* __restrict__ lin_edge,
                                               const float* __restrict__ att_edge,
                                               int* __restrict__ counts,
                                               int* __restrict__ roff,
                                               float* __restrict__ meanb,
                                               float* __restrict__ cedge) {
    int blk = blockIdx.x;
    int t = threadIdx.x;
    if (blk < HIST_BLOCKS) {
        // ---- mean partial: batch blk>>6, slice blk&63 (10000 floats contiguous)
        {
            int b = blk >> 6, sl = blk & 63;
            const float4* base = (const float4*)(eattr + (size_t)b * E + sl * 10000);
            float s = 0.f;
            for (int i = t; i < 2500; i += 256) {
                float4 v = base[i];
                s += (v.x + v.y) + (v.z + v.w);
            }
            __shared__ float sh[256];
            sh[t] = s;
            __syncthreads();
            for (int d = 128; d > 0; d >>= 1) {
                if (t < d) sh[t] += sh[t + d];
                __syncthreads();
            }
            if (t == 0) atomicAdd(&meanb[b], sh[0]);
        }
        // ---- histogram
        for (int e = blk * 256 + t; e < E; e += HIST_BLOCKS * 256)
            atomicAdd(&counts[edst[e]], 1);
    } else if (blk < HIST_BLOCKS + 8) {
        int r = (blk - HIST_BLOCKS) * 256 + t;
        if (r > NREG) return;
        int lo = 0, hi = E;
        while (lo < hi) {
            int mid = (lo + hi) >> 1;
            if (esrc[mid] < r) lo = mid + 1; else hi = mid;
        }
        roff[r] = lo;
    } else {
        if (t == 0) {
            float s = 0.f;
            for (int f = 0; f < F; ++f) s += lin_edge[f] * att_edge[f];
            *cedge = s;
        }
    }
}

// ---------------- single-block exclusive scan ----------------
__global__ __launch_bounds__(1024) void k_scan(const int* __restrict__ in,
                                               int* __restrict__ out, int n) {
    __shared__ int sh[1024];
    int t = threadIdx.x;
    int chunk = (n + 1023) / 1024;
    int lo = t * chunk;
    int hi = lo + chunk; if (hi > n) hi = n;
    int local = 0;
    for (int i = lo; i < hi; ++i) local += in[i];
    sh[t] = local;
    __syncthreads();
    for (int d = 1; d < 1024; d <<= 1) {
        int v = (t >= d) ? sh[t - d] : 0;
        __syncthreads();
        sh[t] += v;
        __syncthreads();
    }
    int run = (t == 0) ? 0 : sh[t - 1];
    for (int i = lo; i < hi; ++i) { out[i] = run; run += in[i]; }
    if (t == 1023) out[n] = sh[1023];
}

// ---------------- prep2: fused  scatter | bucket ----------------
// csr_se[pos] = {src_node, edge_id}
__global__ __launch_bounds__(256) void k_prep2(const int* __restrict__ esrc,
                                               const int* __restrict__ edst,
                                               const int* __restrict__ off,
                                               int* __restrict__ cursor,
                                               int2* __restrict__ csr_se,
                                               const int* __restrict__ roff,
                                               int* __restrict__ boff,
                                               int* __restrict__ pe_dst) {
    __shared__ int cnt[NCHUNK], pref[NCHUNK], cur[NCHUNK];
    int blk = blockIdx.x;
    int t = threadIdx.x;
    if (blk < SCAT_BLOCKS) {
        int e = blk * 256 + t;
        for (; e < E; e += SCAT_BLOCKS * 256) {
            int d = edst[e];
            int pos = off[d] + atomicAdd(&cursor[d], 1);
            csr_se[pos] = make_int2(esrc[e], e);
        }
    } else {
        int r = blk - SCAT_BLOCKS;
        int lo = roff[r], hi = roff[r + 1];
        if (t < NCHUNK) { cnt[t] = 0; cur[t] = 0; }
        __syncthreads();
        for (int e = lo + t; e < hi; e += 256)
            atomicAdd(&cnt[edst[e] / CS], 1);
        __syncthreads();
        if (t == 0) {
            int run = 0;
            #pragma unroll
            for (int c = 0; c < NCHUNK; ++c) { pref[c] = run; run += cnt[c]; }
        }
        __syncthreads();
        if (t < NCHUNK) boff[r * NCHUNK + t] = lo + pref[t];
        if (r == 0 && t == 0) boff[NREG * NCHUNK] = E;
        for (int e = lo + t; e < hi; e += 256) {
            int d = edst[e];
            int c = d / CS;
            int pos = lo + pref[c] + atomicAdd(&cur[c], 1);
            pe_dst[pos] = d;
        }
    }
}

// ---------------- coalesced transpose: ew16[e][b] = c * eattr[b][e] (fp16) ----
__global__ __launch_bounds__(256) void k_trans(const float* __restrict__ eattr,
                                               const float* __restrict__ cedge,
                                               __half* __restrict__ ew) {
    __shared__ float tile[256][17];
    int e0 = blockIdx.x * 256;
    int t = threadIdx.x;
    #pragma unroll
    for (int b = 0; b < B; ++b)
        tile[t][b] = eattr[(size_t)b * E + e0 + t];
    __syncthreads();
    float c = *cedge;
    #pragma unroll
    for (int p = 0; p < 4; ++p) {
        int i4 = (p * 256 + t) * 4;
        int el = i4 >> 4, b0 = i4 & 15;
        uint2 o;
        o.x = f16pair(c * tile[el][b0 + 0], c * tile[el][b0 + 1]);
        o.y = f16pair(c * tile[el][b0 + 2], c * tile[el][b0 + 3]);
        *(uint2*)&ew[(size_t)e0 * 16 + i4] = o;
    }
}

// ---------------- h = x @ W -> f16 [n][B][F]; fused a_src/a_dst ----------------
#define XS_LD 260
__global__ __launch_bounds__(256) void k_gemm(const float* __restrict__ x,
                                              const float* __restrict__ W,
                                              const float* __restrict__ att_src,
                                              const float* __restrict__ att_dst,
                                              uint* __restrict__ hu,
                                              float* __restrict__ a_src,
                                              float* __restrict__ a_dst) {
    __shared__ float Ws[DIN * F];
    __shared__ float xs[32 * XS_LD];
    int t = threadIdx.x;
    int row0 = blockIdx.x * 256;      // flattened b*N + n
    #pragma unroll
    for (int j = 0; j < 4; ++j) {
        int idx = (t + 256 * j) * 4;
        *(float4*)&Ws[idx] = *(const float4*)&W[idx];
    }
    const int lr = t & 63;
    const int fg = t >> 6;            // wave-uniform
    float acc[4][8];
    #pragma unroll
    for (int i = 0; i < 4; ++i)
        #pragma unroll
        for (int j = 0; j < 8; ++j) acc[i][j] = 0.f;

    for (int kc = 0; kc < 4; ++kc) {
        __syncthreads();
        #pragma unroll
        for (int j = 0; j < 8; ++j) {
            int p = t + 256 * j;
            int row = p >> 3;
            int kk  = (p & 7) * 4;
            float4 g = *(const float4*)&x[(size_t)(row0 + row) * DIN + kc * 32 + kk];
            xs[(kk + 0) * XS_LD + row] = g.x;
            xs[(kk + 1) * XS_LD + row] = g.y;
            xs[(kk + 2) * XS_LD + row] = g.z;
            xs[(kk + 3) * XS_LD + row] = g.w;
        }
        __syncthreads();
        #pragma unroll
        for (int k = 0; k < 32; ++k) {
            float4 xv = *(float4*)&xs[k * XS_LD + 4 * lr];
            float4 w0 = *(float4*)&Ws[(kc * 32 + k) * F + fg * 8];
            float4 w1 = *(float4*)&Ws[(kc * 32 + k) * F + fg * 8 + 4];
            float xr[4] = {xv.x, xv.y, xv.z, xv.w};
            float wr[8] = {w0.x, w0.y, w0.z, w0.w, w1.x, w1.y, w1.z, w1.w};
            #pragma unroll
            for (int i = 0; i < 4; ++i)
                #pragma unroll
                for (int j = 0; j < 8; ++j)
                    acc[i][j] = fmaf(xr[i], wr[j], acc[i][j]);
        }
    }
    #pragma unroll
    for (int i = 0; i < 4; ++i) {
        int row = row0 + lr * 4 + i;
        int b = row / N;
        int n = row - b * N;
        uint4 o;
        o.x = f16pair(acc[i][0], acc[i][1]);
        o.y = f16pair(acc[i][2], acc[i][3]);
        o.z = f16pair(acc[i][4], acc[i][5]);
        o.w = f16pair(acc[i][6], acc[i][7]);
        *(uint4*)&hu[(size_t)n * 256 + b * 16 + fg * 4] = o;
    }
    float* red = xs;
    __syncthreads();
    #pragma unroll
    for (int i = 0; i < 4; ++i) {
        float s1 = 0.f, s2 = 0.f;
        #pragma unroll
        for (int j = 0; j < 8; ++j) {
            float as = att_src[fg * 8 + j];
            float ad = att_dst[fg * 8 + j];
            s1 = fmaf(acc[i][j], as, s1);
            s2 = fmaf(acc[i][j], ad, s2);
        }
        red[fg * 256 + lr * 4 + i]        = s1;
        red[1024 + fg * 256 + lr * 4 + i] = s2;
    }
    __syncthreads();
    {
        float s1 = red[t] + red[256 + t] + red[512 + t] + red[768 + t];
        float s2 = red[1024 + t] + red[1280 + t] + red[1536 + t] + red[1792 + t];
        int row = row0 + t;
        int b = row / N;
        int n = row - b * N;
        a_src[(size_t)n * B + b] = s1;
        a_dst[(size_t)n * B + b] = s2;
    }
}

// ---------------- rep: edge-partitioned waves, DPP weight broadcast,
//                  SGPR-base dwordx4 row loads, v_pk_fma_f16 accumulate ------
// lane l: b = l>>2 (batch), q = l&3 (f-octet / edge-slot)
// wave wid handles edge groups [lo + wid*4 + 16k, +4)
__global__ __launch_bounds__(256) void k_rep(
    const uint4* __restrict__ hu4, const float* __restrict__ a_src,
    const float* __restrict__ a_dst, const __half* __restrict__ ew,
    const int2* __restrict__ csr_se, const float* __restrict__ bias,
    const float* __restrict__ meanb, const float* __restrict__ cedge,
    const int* __restrict__ dst_off, uint4* __restrict__ repu4) {
    __shared__ uint4 lacc[4][64];
    __shared__ float lsum[4][64];
    int i = blockIdx.x;
    int t = threadIdx.x;
    int wid = t >> 6;
    int l = t & 63;
    int b = l >> 2;
    int q = l & 3;
    float adst = a_dst[(size_t)i * B + b];
    int lo = dst_off[i], hi = dst_off[i + 1];
    float ssum = 0.f;
    __half2 zero2 = __half2half2(__float2half(0.f));
    __half2 acc0 = zero2, acc1 = zero2, acc2 = zero2, acc3 = zero2;

    for (int g0 = lo + wid * 4; g0 < hi; g0 += 16) {
        // phase A: this wave's 4 edges x 16 batches -> one weight per lane
        int jj = g0 + q;
        int idx = jj < hi ? jj : hi - 1;
        int2 se = csr_se[idx];
        float a2 = a_src[(size_t)se.x * B + b] + adst
                 + __half2float(ew[(size_t)se.y * B + b]);
        a2 = a2 > 0.f ? a2 : NEG * a2;
        float wv = (jj < hi) ? __expf(a2) : 0.f;
        ssum += wv;
        __half2 w2 = __half2half2(__float2half(wv));
        uint w2u = *(uint*)&w2;
        // phase B: per edge e: DPP quad-broadcast w (same b within quad),
        // readlane src -> scalar base, one dwordx4 row load, 4 pk_fma
#define REP_STEP(EIDX, CTRL) { \
        int wei = __builtin_amdgcn_mov_dpp((int)w2u, CTRL, 0xf, 0xf, true); \
        __half2 weh = *(__half2*)&wei; \
        int sre = __builtin_amdgcn_readlane(se.x, EIDX); \
        uint4 hv = hu4[(size_t)sre * 64 + l]; \
        acc0 = __hfma2(weh, *(__half2*)&hv.x, acc0); \
        acc1 = __hfma2(weh, *(__half2*)&hv.y, acc1); \
        acc2 = __hfma2(weh, *(__half2*)&hv.z, acc2); \
        acc3 = __hfma2(weh, *(__half2*)&hv.w, acc3); }
        REP_STEP(0, 0)      // quad_perm {0,0,0,0}
        REP_STEP(1, 85)     // quad_perm {1,1,1,1}
        REP_STEP(2, 170)    // quad_perm {2,2,2,2}
        REP_STEP(3, 255)    // quad_perm {3,3,3,3}
#undef REP_STEP
    }
    // denominator partial: reduce over the 4 edge-slots (same b within quad)
    ssum += __shfl_xor(ssum, 1, 64);
    ssum += __shfl_xor(ssum, 2, 64);
    if (wid) {
        uint4 a;
        a.x = *(uint*)&acc0; a.y = *(uint*)&acc1;
        a.z = *(uint*)&acc2; a.w = *(uint*)&acc3;
        lacc[wid][l] = a;
        lsum[wid][l] = ssum;
    }
    __syncthreads();
    if (wid == 0) {
        float2 p0 = __half22float2(acc0);
        float2 p1 = __half22float2(acc1);
        float2 p2 = __half22float2(acc2);
        float2 p3 = __half22float2(acc3);
        #pragma unroll
        for (int ww = 1; ww < 4; ++ww) {
            uint4 a = lacc[ww][l];
            float2 u;
            u = h2f2(a.x); p0.x += u.x; p0.y += u.y;
            u = h2f2(a.y); p1.x += u.x; p1.y += u.y;
            u = h2f2(a.z); p2.x += u.x; p2.y += u.y;
            u = h2f2(a.w); p3.x += u.x; p3.y += u.y;
            ssum += lsum[ww][l];
        }
        // self-loop term
        float c = *cedge;
        float meanv = meanb[b] * (1.f / (float)E);
        float al = a_src[(size_t)i * B + b] + adst + meanv * c;
        al = al > 0.f ? al : NEG * al;
        float ws = __expf(al);
        uint4 hv = hu4[(size_t)i * 64 + l];
        float2 u;
        u = h2f2(hv.x); p0.x = fmaf(ws, u.x, p0.x); p0.y = fmaf(ws, u.y, p0.y);
        u = h2f2(hv.y); p1.x = fmaf(ws, u.x, p1.x); p1.y = fmaf(ws, u.y, p1.y);
        u = h2f2(hv.z); p2.x = fmaf(ws, u.x, p2.x); p2.y = fmaf(ws, u.y, p2.y);
        u = h2f2(hv.w); p3.x = fmaf(ws, u.x, p3.x); p3.y = fmaf(ws, u.y, p3.y);
        float inv = 1.f / (ssum + ws);
        const float4* bias4 = (const float4*)bias;
        float4 ba = bias4[q * 2];
        float4 bb = bias4[q * 2 + 1];
        uint4 o;
        o.x = f16pair(fmaf(p0.x, inv, ba.x), fmaf(p0.y, inv, ba.y));
        o.y = f16pair(fmaf(p1.x, inv, ba.z), fmaf(p1.y, inv, ba.w));
        o.z = f16pair(fmaf(p2.x, inv, bb.x), fmaf(p2.y, inv, bb.y));
        o.w = f16pair(fmaf(p3.x, inv, bb.z), fmaf(p3.y, inv, bb.w));
        repu4[(size_t)i * 64 + l] = o;
    }
}

// ---------------- chunked pooling: block = (chunk, regulon), 8-deep pipeline ----------------
__global__ __launch_bounds__(256) void k_pool(const uint* __restrict__ repu,
                                              const int* __restrict__ boff,
                                              const int* __restrict__ pe_dst,
                                              float* __restrict__ partial) {
    int key = blockIdx.x;            // c * NREG + r (chunk-major dispatch)
    int c = key / NREG;
    int r = key - c * NREG;
    int idx = r * NCHUNK + c;        // boff is regulon-major
    int t = threadIdx.x;
    int lo = boff[idx], hi = boff[idx + 1];
    float acc0 = 0.f, acc1 = 0.f;
    int e = lo;
    for (; e + 8 <= hi; e += 8) {
        int d0 = pe_dst[e+0], d1 = pe_dst[e+1], d2 = pe_dst[e+2], d3 = pe_dst[e+3];
        int d4 = pe_dst[e+4], d5 = pe_dst[e+5], d6 = pe_dst[e+6], d7 = pe_dst[e+7];
        uint v0 = repu[(size_t)d0 * 256 + t];
        uint v1 = repu[(size_t)d1 * 256 + t];
        uint v2 = repu[(size_t)d2 * 256 + t];
        uint v3 = repu[(size_t)d3 * 256 + t];
        uint v4 = repu[(size_t)d4 * 256 + t];
        uint v5 = repu[(size_t)d5 * 256 + t];
        uint v6 = repu[(size_t)d6 * 256 + t];
        uint v7 = repu[(size_t)d7 * 256 + t];
        float2 u0 = h2f2(v0), u1 = h2f2(v1), u2 = h2f2(v2), u3 = h2f2(v3);
        float2 u4 = h2f2(v4), u5 = h2f2(v5), u6 = h2f2(v6), u7 = h2f2(v7);
        acc0 += (u0.x + u1.x) + (u2.x + u3.x) + (u4.x + u5.x) + (u6.x + u7.x);
        acc1 += (u0.y + u1.y) + (u2.y + u3.y) + (u4.y + u5.y) + (u6.y + u7.y);
    }
    for (; e < hi; ++e) {
        int d = pe_dst[e];
        float2 u = h2f2(repu[(size_t)d * 256 + t]);
        acc0 += u.x;
        acc1 += u.y;
    }
    float2 o = {acc0, acc1};
    *(float2*)&partial[((size_t)r * NCHUNK + c) * BF + 2 * t] = o;
}

__global__ __launch_bounds__(256) void k_combine(const uint* __restrict__ repu,
                                                 const float* __restrict__ partial,
                                                 float* __restrict__ out) {
    int r = blockIdx.x;
    int t = threadIdx.x;
    int b  = t >> 4;
    int fp = t & 15;
    float2 u = h2f2(repu[(size_t)r * 256 + t]);   // self term
    float s0 = u.x, s1 = u.y;
    #pragma unroll
    for (int c = 0; c < NCHUNK; ++c) {
        float2 p = *(const float2*)&partial[((size_t)r * NCHUNK + c) * BF + 2 * t];
        s0 += p.x; s1 += p.y;
    }
    float2 o = {s0, s1};
    *(float2*)&out[(size_t)b * NREG * F + r * F + 2 * fp] = o;
}

extern "C" void kernel_launch(void* const* d_in, const int* in_sizes, int n_in,
                              void* d_out, int out_size, void* d_ws, size_t ws_size,
                              hipStream_t stream) {
    const float* x        = (const float*)d_in[0];
    const float* eattr    = (const float*)d_in[1];
    const float* W        = (const float*)d_in[2];
    const float* att_src  = (const float*)d_in[3];
    const float* att_dst  = (const float*)d_in[4];
    const float* lin_edge = (const float*)d_in[5];
    const float* att_edge = (const float*)d_in[6];
    const float* bias     = (const float*)d_in[7];
    const int*   esrc     = (const int*)d_in[8];
    const int*   edst     = (const int*)d_in[9];
    float* out = (float*)d_out;

    char* ws = (char*)d_ws;
    size_t off = 0;
    auto alloc = [&](size_t bytes) -> void* {
        void* p = ws + off;
        off = (off + bytes + 255) & ~(size_t)255;
        return p;
    };
    uint*  hu    = (uint*)alloc((size_t)N * 256 * 4);          // 20.5 MB f16 h
    uint*  repu  = (uint*)alloc((size_t)N * 256 * 4);          // 20.5 MB f16 rep
    __half* ew   = (__half*)alloc((size_t)E * B * 2);          // 20.5 MB f16 c*eattr^T
    float* partial = (float*)alloc((size_t)NREG * NCHUNK * BF * 4); // 32.8 MB
    float* a_src = (float*)alloc((size_t)N * B * 4);
    float* a_dst = (float*)alloc((size_t)N * B * 4);
    int* dst_off = (int*)alloc((size_t)(N + 1) * 4);
    int* roff    = (int*)alloc((size_t)(NREG + 1) * 4);
    int2* csr_se = (int2*)alloc((size_t)E * 8);
    int* pe_dst  = (int*)alloc((size_t)E * 4);
    int* boff    = (int*)alloc((size_t)(NREG * NCHUNK + 1) * 4);
    char* zbase   = ws + off;
    int* counts   = (int*)alloc((size_t)N * 4);
    int* cursor   = (int*)alloc((size_t)N * 4);
    float* meanb  = (float*)alloc((size_t)B * 4);
    float* cedge  = (float*)alloc(4);
    size_t zbytes = (size_t)((ws + off) - zbase);

    hipMemsetAsync(zbase, 0, zbytes, stream);

    k_prep1<<<HIST_BLOCKS + 8 + 1, 256, 0, stream>>>(esrc, edst, eattr, lin_edge,
                                                     att_edge, counts, roff,
                                                     meanb, cedge);
    k_scan<<<1, 1024, 0, stream>>>(counts, dst_off, N);
    k_prep2<<<SCAT_BLOCKS + NREG, 256, 0, stream>>>(esrc, edst, dst_off, cursor,
                                                    csr_se, roff, boff, pe_dst);
    k_gemm<<<(B * N) / 256, 256, 0, stream>>>(x, W, att_src, att_dst,
                                              hu, a_src, a_dst);
    k_trans<<<E / 256, 256, 0, stream>>>(eattr, cedge, ew);
    k_rep<<<N, 256, 0, stream>>>((const uint4*)hu, a_src, a_dst, ew, csr_se,
                                 bias, meanb, cedge, dst_off, (uint4*)repu);
    k_pool<<<NREG * NCHUNK, 256, 0, stream>>>(repu, boff, pe_dst, partial);
    k_combine<<<NREG, 256, 0, stream>>>(repu, partial, out);
}

// Round 8
// 484.451 us; speedup vs baseline: 1.2668x; 1.0093x over previous
//
#include <hip/hip_runtime.h>
#include <hip/hip_fp16.h>
#include <math.h>

#define B    16
#define N    20000
#define E    640000
#define NREG 2000
#define DIN  128
#define F    32
#define NEG  0.2f
#define BF   (B * F)          // 512 values per node row; f16 = 1KB
#define NCHUNK 8
#define CS   2500             // nodes per chunk (2500*1KB = 2.44 MB repu slice)
#define HIST_BLOCKS 1024
#define SCAT_BLOCKS 1024
#define GEMM_BLOCKS 1250      // (B*N)/256

typedef unsigned int uint;
typedef _Float16 half8 __attribute__((ext_vector_type(8)));
typedef float f32x4 __attribute__((ext_vector_type(4)));

__device__ inline uint f16pair(float a, float b) {
    __half2 h = __floats2half2_rn(a, b);
    return *(uint*)&h;
}
__device__ inline float2 h2f2(uint v) {
    return __half22float2(*(__half2*)&v);
}

// ---------------- prep1: fused  hist+mean | roff | cedge ----------------
__global__ __launch_bounds__(256) void k_prep1(const int* __restrict__ esrc,
                                               const int* __restrict__ edst,
                                               const float* __restrict__ eattr,
                                               const float* __restrict__ lin_edge,
                                               const float* __restrict__ att_edge,
                                               int* __restrict__ counts,
                                               int* __restrict__ roff,
                                               float* __restrict__ meanb,
                                               float* __restrict__ cedge) {
    int blk = blockIdx.x;
    int t = threadIdx.x;
    if (blk < HIST_BLOCKS) {
        // ---- mean partial: batch blk>>6, slice blk&63 (10000 floats contiguous)
        {
            int b = blk >> 6, sl = blk & 63;
            const float4* base = (const float4*)(eattr + (size_t)b * E + sl * 10000);
            float s = 0.f;
            for (int i = t; i < 2500; i += 256) {
                float4 v = base[i];
                s += (v.x + v.y) + (v.z + v.w);
            }
            __shared__ float sh[256];
            sh[t] = s;
            __syncthreads();
            for (int d = 128; d > 0; d >>= 1) {
                if (t < d) sh[t] += sh[t + d];
                __syncthreads();
            }
            if (t == 0) atomicAdd(&meanb[b], sh[0]);
        }
        // ---- histogram
        for (int e = blk * 256 + t; e < E; e += HIST_BLOCKS * 256)
            atomicAdd(&counts[edst[e]], 1);
    } else if (blk < HIST_BLOCKS + 8) {
        int r = (blk - HIST_BLOCKS) * 256 + t;
        if (r > NREG) return;
        int lo = 0, hi = E;
        while (lo < hi) {
            int mid = (lo + hi) >> 1;
            if (esrc[mid] < r) lo = mid + 1; else hi = mid;
        }
        roff[r] = lo;
    } else {
        if (t == 0) {
            float s = 0.f;
            for (int f = 0; f < F; ++f) s += lin_edge[f] * att_edge[f];
            *cedge = s;
        }
    }
}

// ---------------- single-block exclusive scan ----------------
__global__ __launch_bounds__(1024) void k_scan(const int* __restrict__ in,
                                               int* __restrict__ out, int n) {
    __shared__ int sh[1024];
    int t = threadIdx.x;
    int chunk = (n + 1023) / 1024;
    int lo = t * chunk;
    int hi = lo + chunk; if (hi > n) hi = n;
    int local = 0;
    for (int i = lo; i < hi; ++i) local += in[i];
    sh[t] = local;
    __syncthreads();
    for (int d = 1; d < 1024; d <<= 1) {
        int v = (t >= d) ? sh[t - d] : 0;
        __syncthreads();
        sh[t] += v;
        __syncthreads();
    }
    int run = (t == 0) ? 0 : sh[t - 1];
    for (int i = lo; i < hi; ++i) { out[i] = run; run += in[i]; }
    if (t == 1023) out[n] = sh[1023];
}

// ---------------- prep2: fused  scatter | bucket ----------------
// csr_se[pos] = {src_node, edge_id}
__global__ __launch_bounds__(256) void k_prep2(const int* __restrict__ esrc,
                                               const int* __restrict__ edst,
                                               const int* __restrict__ off,
                                               int* __restrict__ cursor,
                                               int2* __restrict__ csr_se,
                                               const int* __restrict__ roff,
                                               int* __restrict__ boff,
                                               int* __restrict__ pe_dst) {
    __shared__ int cnt[NCHUNK], pref[NCHUNK], cur[NCHUNK];
    int blk = blockIdx.x;
    int t = threadIdx.x;
    if (blk < SCAT_BLOCKS) {
        int e = blk * 256 + t;
        for (; e < E; e += SCAT_BLOCKS * 256) {
            int d = edst[e];
            int pos = off[d] + atomicAdd(&cursor[d], 1);
            csr_se[pos] = make_int2(esrc[e], e);
        }
    } else {
        int r = blk - SCAT_BLOCKS;
        int lo = roff[r], hi = roff[r + 1];
        if (t < NCHUNK) { cnt[t] = 0; cur[t] = 0; }
        __syncthreads();
        for (int e = lo + t; e < hi; e += 256)
            atomicAdd(&cnt[edst[e] / CS], 1);
        __syncthreads();
        if (t == 0) {
            int run = 0;
            #pragma unroll
            for (int c = 0; c < NCHUNK; ++c) { pref[c] = run; run += cnt[c]; }
        }
        __syncthreads();
        if (t < NCHUNK) boff[r * NCHUNK + t] = lo + pref[t];
        if (r == 0 && t == 0) boff[NREG * NCHUNK] = E;
        for (int e = lo + t; e < hi; e += 256) {
            int d = edst[e];
            int c = d / CS;
            int pos = lo + pref[c] + atomicAdd(&cur[c], 1);
            pe_dst[pos] = d;
        }
    }
}

// ---------------- fused: MFMA gemm (blocks < GEMM_BLOCKS) | trans ----------------
// gemm: h = x @ W -> f16 [n][B][F] + fused a_src/a_dst, via mfma_f32_16x16x32_f16
// trans: ew16[e][b] = c * eattr[b][e]
__global__ __launch_bounds__(256) void k_gt(const float* __restrict__ x,
                                            const float* __restrict__ W,
                                            const float* __restrict__ att_src,
                                            const float* __restrict__ att_dst,
                                            const float* __restrict__ eattr,
                                            const float* __restrict__ cedge,
                                            uint* __restrict__ hu,
                                            float* __restrict__ a_src,
                                            float* __restrict__ a_dst,
                                            __half* __restrict__ ew) {
    __shared__ uint smem[11392];       // 45.6 KB, aliased by both branches
    int blk = blockIdx.x;
    int t = threadIdx.x;
    if (blk < GEMM_BLOCKS) {
        _Float16* Wt = (_Float16*)smem;            // [32][136] f16 = 8704 B
        float* hbuf = (float*)(smem + 2176);       // 4 waves x [64][36] f32
        int wid = t >> 6;
        int l = t & 63;
        int row0 = blk * 256;
        // transpose W (f32 [128][32]) -> Wt (f16 [c][k], stride 136)
        #pragma unroll
        for (int p = 0; p < 16; ++p) {
            int idx = p * 256 + t;                 // idx = k*32 + c
            Wt[(idx & 31) * 136 + (idx >> 5)] = (_Float16)W[idx];
        }
        __syncthreads();
        int col = l & 15, kg = l >> 4;
        // B fragments: B[k=(kg*8+i)][col] for col-tile ct, k-chunk kc
        half8 bf[2][4];
        #pragma unroll
        for (int ct = 0; ct < 2; ++ct)
            #pragma unroll
            for (int kc = 0; kc < 4; ++kc)
                bf[ct][kc] = *(half8*)&Wt[(ct * 16 + col) * 136 + kc * 32 + kg * 8];
        f32x4 acc[4][2];
        #pragma unroll
        for (int rt = 0; rt < 4; ++rt)
            #pragma unroll
            for (int ct = 0; ct < 2; ++ct)
                acc[rt][ct] = (f32x4){0.f, 0.f, 0.f, 0.f};
        int rbase = row0 + wid * 64;
        #pragma unroll
        for (int kc = 0; kc < 4; ++kc) {
            half8 afr[4];
            #pragma unroll
            for (int rt = 0; rt < 4; ++rt) {
                const float* xp = &x[(size_t)(rbase + rt * 16 + col) * DIN + kc * 32 + kg * 8];
                float4 xa = *(const float4*)xp;
                float4 xb = *(const float4*)(xp + 4);
                half8 a;
                a[0] = (_Float16)xa.x; a[1] = (_Float16)xa.y;
                a[2] = (_Float16)xa.z; a[3] = (_Float16)xa.w;
                a[4] = (_Float16)xb.x; a[5] = (_Float16)xb.y;
                a[6] = (_Float16)xb.z; a[7] = (_Float16)xb.w;
                afr[rt] = a;
            }
            #pragma unroll
            for (int rt = 0; rt < 4; ++rt)
                #pragma unroll
                for (int ct = 0; ct < 2; ++ct)
                    acc[rt][ct] = __builtin_amdgcn_mfma_f32_16x16x32_f16(
                        afr[rt], bf[ct][kc], acc[rt][ct], 0, 0, 0);
        }
        // stage acc through per-wave LDS tile (no barrier: same-wave RAW)
        float* hb = hbuf + wid * (64 * 36);
        #pragma unroll
        for (int rt = 0; rt < 4; ++rt)
            #pragma unroll
            for (int ct = 0; ct < 2; ++ct)
                #pragma unroll
                for (int m = 0; m < 4; ++m)
                    hb[(rt * 16 + kg * 4 + m) * 36 + ct * 16 + col] = acc[rt][ct][m];
        // lane l owns node-row rbase+l: pack f16 + attn dots + store
        int row_g = rbase + l;
        int b = row_g / N;
        int n = row_g - b * N;
        const float* hr = hb + l * 36;
        float s1 = 0.f, s2 = 0.f;
        uint ou[16];
        #pragma unroll
        for (int j = 0; j < 16; ++j) {
            float e0 = hr[2 * j], e1 = hr[2 * j + 1];
            ou[j] = f16pair(e0, e1);
            s1 = fmaf(e0, att_src[2 * j], fmaf(e1, att_src[2 * j + 1], s1));
            s2 = fmaf(e0, att_dst[2 * j], fmaf(e1, att_dst[2 * j + 1], s2));
        }
        uint4* dst = (uint4*)&hu[(size_t)n * 256 + b * 16];
        dst[0] = make_uint4(ou[0], ou[1], ou[2], ou[3]);
        dst[1] = make_uint4(ou[4], ou[5], ou[6], ou[7]);
        dst[2] = make_uint4(ou[8], ou[9], ou[10], ou[11]);
        dst[3] = make_uint4(ou[12], ou[13], ou[14], ou[15]);
        a_src[(size_t)n * B + b] = s1;
        a_dst[(size_t)n * B + b] = s2;
    } else {
        float (*tile)[17] = (float(*)[17])smem;    // 256x17 f32 = 17408 B
        int e0 = (blk - GEMM_BLOCKS) * 256;
        #pragma unroll
        for (int b = 0; b < B; ++b)
            tile[t][b] = eattr[(size_t)b * E + e0 + t];
        __syncthreads();
        float c = *cedge;
        #pragma unroll
        for (int p = 0; p < 4; ++p) {
            int i4 = (p * 256 + t) * 4;
            int el = i4 >> 4, b0 = i4 & 15;
            uint2 o;
            o.x = f16pair(c * tile[el][b0 + 0], c * tile[el][b0 + 1]);
            o.y = f16pair(c * tile[el][b0 + 2], c * tile[el][b0 + 3]);
            *(uint2*)&ew[(size_t)e0 * 16 + i4] = o;
        }
    }
}

// ---------------- rep: edge-partitioned waves, DPP weight broadcast,
//                  SGPR-base dwordx4 row loads, v_pk_fma_f16 accumulate ------
__global__ __launch_bounds__(256) void k_rep(
    const uint4* __restrict__ hu4, const float* __restrict__ a_src,
    const float* __restrict__ a_dst, const __half* __restrict__ ew,
    const int2* __restrict__ csr_se, const float* __restrict__ bias,
    const float* __restrict__ meanb, const float* __restrict__ cedge,
    const int* __restrict__ dst_off, uint4* __restrict__ repu4) {
    __shared__ uint4 lacc[4][64];
    __shared__ float lsum[4][64];
    int i = blockIdx.x;
    int t = threadIdx.x;
    int wid = t >> 6;
    int l = t & 63;
    int b = l >> 2;
    int q = l & 3;
    float adst = a_dst[(size_t)i * B + b];
    int lo = dst_off[i], hi = dst_off[i + 1];
    float ssum = 0.f;
    __half2 zero2 = __half2half2(__float2half(0.f));
    __half2 acc0 = zero2, acc1 = zero2, acc2 = zero2, acc3 = zero2;

    for (int g0 = lo + wid * 4; g0 < hi; g0 += 16) {
        int jj = g0 + q;
        int idx = jj < hi ? jj : hi - 1;
        int2 se = csr_se[idx];
        float a2 = a_src[(size_t)se.x * B + b] + adst
                 + __half2float(ew[(size_t)se.y * B + b]);
        a2 = a2 > 0.f ? a2 : NEG * a2;
        float wv = (jj < hi) ? __expf(a2) : 0.f;
        ssum += wv;
        __half2 w2 = __half2half2(__float2half(wv));
        uint w2u = *(uint*)&w2;
#define REP_STEP(EIDX, CTRL) { \
        int wei = __builtin_amdgcn_mov_dpp((int)w2u, CTRL, 0xf, 0xf, true); \
        __half2 weh = *(__half2*)&wei; \
        int sre = __builtin_amdgcn_readlane(se.x, EIDX); \
        uint4 hv = hu4[(size_t)sre * 64 + l]; \
        acc0 = __hfma2(weh, *(__half2*)&hv.x, acc0); \
        acc1 = __hfma2(weh, *(__half2*)&hv.y, acc1); \
        acc2 = __hfma2(weh, *(__half2*)&hv.z, acc2); \
        acc3 = __hfma2(weh, *(__half2*)&hv.w, acc3); }
        REP_STEP(0, 0)
        REP_STEP(1, 85)
        REP_STEP(2, 170)
        REP_STEP(3, 255)
#undef REP_STEP
    }
    ssum += __shfl_xor(ssum, 1, 64);
    ssum += __shfl_xor(ssum, 2, 64);
    if (wid) {
        uint4 a;
        a.x = *(uint*)&acc0; a.y = *(uint*)&acc1;
        a.z = *(uint*)&acc2; a.w = *(uint*)&acc3;
        lacc[wid][l] = a;
        lsum[wid][l] = ssum;
    }
    __syncthreads();
    if (wid == 0) {
        float2 p0 = __half22float2(acc0);
        float2 p1 = __half22float2(acc1);
        float2 p2 = __half22float2(acc2);
        float2 p3 = __half22float2(acc3);
        #pragma unroll
        for (int ww = 1; ww < 4; ++ww) {
            uint4 a = lacc[ww][l];
            float2 u;
            u = h2f2(a.x); p0.x += u.x; p0.y += u.y;
            u = h2f2(a.y); p1.x += u.x; p1.y += u.y;
            u = h2f2(a.z); p2.x += u.x; p2.y += u.y;
            u = h2f2(a.w); p3.x += u.x; p3.y += u.y;
            ssum += lsum[ww][l];
        }
        float c = *cedge;
        float meanv = meanb[b] * (1.f / (float)E);
        float al = a_src[(size_t)i * B + b] + adst + meanv * c;
        al = al > 0.f ? al : NEG * al;
        float ws = __expf(al);
        uint4 hv = hu4[(size_t)i * 64 + l];
        float2 u;
        u = h2f2(hv.x); p0.x = fmaf(ws, u.x, p0.x); p0.y = fmaf(ws, u.y, p0.y);
        u = h2f2(hv.y); p1.x = fmaf(ws, u.x, p1.x); p1.y = fmaf(ws, u.y, p1.y);
        u = h2f2(hv.z); p2.x = fmaf(ws, u.x, p2.x); p2.y = fmaf(ws, u.y, p2.y);
        u = h2f2(hv.w); p3.x = fmaf(ws, u.x, p3.x); p3.y = fmaf(ws, u.y, p3.y);
        float inv = 1.f / (ssum + ws);
        const float4* bias4 = (const float4*)bias;
        float4 ba = bias4[q * 2];
        float4 bb = bias4[q * 2 + 1];
        uint4 o;
        o.x = f16pair(fmaf(p0.x, inv, ba.x), fmaf(p0.y, inv, ba.y));
        o.y = f16pair(fmaf(p1.x, inv, ba.z), fmaf(p1.y, inv, ba.w));
        o.z = f16pair(fmaf(p2.x, inv, bb.x), fmaf(p2.y, inv, bb.y));
        o.w = f16pair(fmaf(p3.x, inv, bb.z), fmaf(p3.y, inv, bb.w));
        repu4[(size_t)i * 64 + l] = o;
    }
}

// ---------------- chunked pooling: block = (chunk, regulon), 8-deep pipeline ----------------
__global__ __launch_bounds__(256) void k_pool(const uint* __restrict__ repu,
                                              const int* __restrict__ boff,
                                              const int* __restrict__ pe_dst,
                                              float* __restrict__ partial) {
    int key = blockIdx.x;            // c * NREG + r (chunk-major dispatch)
    int c = key / NREG;
    int r = key - c * NREG;
    int idx = r * NCHUNK + c;        // boff is regulon-major
    int t = threadIdx.x;
    int lo = boff[idx], hi = boff[idx + 1];
    float acc0 = 0.f, acc1 = 0.f;
    int e = lo;
    for (; e + 8 <= hi; e += 8) {
        int d0 = pe_dst[e+0], d1 = pe_dst[e+1], d2 = pe_dst[e+2], d3 = pe_dst[e+3];
        int d4 = pe_dst[e+4], d5 = pe_dst[e+5], d6 = pe_dst[e+6], d7 = pe_dst[e+7];
        uint v0 = repu[(size_t)d0 * 256 + t];
        uint v1 = repu[(size_t)d1 * 256 + t];
        uint v2 = repu[(size_t)d2 * 256 + t];
        uint v3 = repu[(size_t)d3 * 256 + t];
        uint v4 = repu[(size_t)d4 * 256 + t];
        uint v5 = repu[(size_t)d5 * 256 + t];
        uint v6 = repu[(size_t)d6 * 256 + t];
        uint v7 = repu[(size_t)d7 * 256 + t];
        float2 u0 = h2f2(v0), u1 = h2f2(v1), u2 = h2f2(v2), u3 = h2f2(v3);
        float2 u4 = h2f2(v4), u5 = h2f2(v5), u6 = h2f2(v6), u7 = h2f2(v7);
        acc0 += (u0.x + u1.x) + (u2.x + u3.x) + (u4.x + u5.x) + (u6.x + u7.x);
        acc1 += (u0.y + u1.y) + (u2.y + u3.y) + (u4.y + u5.y) + (u6.y + u7.y);
    }
    for (; e < hi; ++e) {
        int d = pe_dst[e];
        float2 u = h2f2(repu[(size_t)d * 256 + t]);
        acc0 += u.x;
        acc1 += u.y;
    }
    float2 o = {acc0, acc1};
    *(float2*)&partial[((size_t)r * NCHUNK + c) * BF + 2 * t] = o;
}

__global__ __launch_bounds__(256) void k_combine(const uint* __restrict__ repu,
                                                 const float* __restrict__ partial,
                                                 float* __restrict__ out) {
    int r = blockIdx.x;
    int t = threadIdx.x;
    int b  = t >> 4;
    int fp = t & 15;
    float2 u = h2f2(repu[(size_t)r * 256 + t]);   // self term
    float s0 = u.x, s1 = u.y;
    #pragma unroll
    for (int c = 0; c < NCHUNK; ++c) {
        float2 p = *(const float2*)&partial[((size_t)r * NCHUNK + c) * BF + 2 * t];
        s0 += p.x; s1 += p.y;
    }
    float2 o = {s0, s1};
    *(float2*)&out[(size_t)b * NREG * F + r * F + 2 * fp] = o;
}

extern "C" void kernel_launch(void* const* d_in, const int* in_sizes, int n_in,
                              void* d_out, int out_size, void* d_ws, size_t ws_size,
                              hipStream_t stream) {
    const float* x        = (const float*)d_in[0];
    const float* eattr    = (const float*)d_in[1];
    const float* W        = (const float*)d_in[2];
    const float* att_src  = (const float*)d_in[3];
    const float* att_dst  = (const float*)d_in[4];
    const float* lin_edge = (const float*)d_in[5];
    const float* att_edge = (const float*)d_in[6];
    const float* bias     = (const float*)d_in[7];
    const int*   esrc     = (const int*)d_in[8];
    const int*   edst     = (const int*)d_in[9];
    float* out = (float*)d_out;

    char* ws = (char*)d_ws;
    size_t off = 0;
    auto alloc = [&](size_t bytes) -> void* {
        void* p = ws + off;
        off = (off + bytes + 255) & ~(size_t)255;
        return p;
    };
    uint*  hu    = (uint*)alloc((size_t)N * 256 * 4);          // 20.5 MB f16 h
    uint*  repu  = (uint*)alloc((size_t)N * 256 * 4);          // 20.5 MB f16 rep
    __half* ew   = (__half*)alloc((size_t)E * B * 2);          // 20.5 MB f16 c*eattr^T
    float* partial = (float*)alloc((size_t)NREG * NCHUNK * BF * 4); // 32.8 MB
    float* a_src = (float*)alloc((size_t)N * B * 4);
    float* a_dst = (float*)alloc((size_t)N * B * 4);
    int* dst_off = (int*)alloc((size_t)(N + 1) * 4);
    int* roff    = (int*)alloc((size_t)(NREG + 1) * 4);
    int2* csr_se = (int2*)alloc((size_t)E * 8);
    int* pe_dst  = (int*)alloc((size_t)E * 4);
    int* boff    = (int*)alloc((size_t)(NREG * NCHUNK + 1) * 4);
    char* zbase   = ws + off;
    int* counts   = (int*)alloc((size_t)N * 4);
    int* cursor   = (int*)alloc((size_t)N * 4);
    float* meanb  = (float*)alloc((size_t)B * 4);
    float* cedge  = (float*)alloc(4);
    size_t zbytes = (size_t)((ws + off) - zbase);

    hipMemsetAsync(zbase, 0, zbytes, stream);

    k_prep1<<<HIST_BLOCKS + 8 + 1, 256, 0, stream>>>(esrc, edst, eattr, lin_edge,
                                                     att_edge, counts, roff,
                                                     meanb, cedge);
    k_scan<<<1, 1024, 0, stream>>>(counts, dst_off, N);
    k_prep2<<<SCAT_BLOCKS + NREG, 256, 0, stream>>>(esrc, edst, dst_off, cursor,
                                                    csr_se, roff, boff, pe_dst);
    k_gt<<<GEMM_BLOCKS + E / 256, 256, 0, stream>>>(x, W, att_src, att_dst,
                                                    eattr, cedge, hu,
                                                    a_src, a_dst, ew);
    k_rep<<<N, 256, 0, stream>>>((const uint4*)hu, a_src, a_dst, ew, csr_se,
                                 bias, meanb, cedge, dst_off, (uint4*)repu);
    k_pool<<<NREG * NCHUNK, 256, 0, stream>>>(repu, boff, pe_dst, partial);
    k_combine<<<NREG, 256, 0, stream>>>(repu, partial, out);
}